// Round 3
// baseline (813.361 us; speedup 1.0000x reference)
//
#include <hip/hip_runtime.h>
#include <hip/hip_bf16.h>

// ---------------------------------------------------------------------------
// S4D stack: encoder GEMM -> 4x[SSM scan conv + GELU -> GLU MFMA GEMM + LN] -> dec
// h stays fp32 (B*L, H); y and Wo are bf16 for the MFMA GEMM.
// Conv = chunked linear recurrence: pass1 chunk states, segmented 3-phase scan,
// pass3 replay with 4-way state split for occupancy.
// ---------------------------------------------------------------------------

constexpr int B_ = 4, L_ = 8192, DIN = 64, H_ = 256, N2_ = 32, NL_ = 4, DOUT = 10;
constexpr int LC = 64, CHK = L_ / LC;     // chunk len 64, 128 chunks
constexpr int M_ = B_ * L_;               // 32768 positions
constexpr int SEG = 8, SEGC = CHK / SEG;  // 8 segments x 16 chunks

// ws layout in float slots
constexpr size_t SZ_H    = (size_t)M_ * H_;
constexpr size_t OFF_H   = 0;
constexpr size_t OFF_Y   = OFF_H + SZ_H;               // bf16 y: SZ_H/2 slots
constexpr size_t OFF_ST  = OFF_Y + SZ_H / 2;
constexpr size_t SZ_ST   = (size_t)B_ * CHK * H_ * N2_ * 2;
constexpr size_t SZ_P    = (size_t)NL_ * H_ * N2_ * 2;
constexpr size_t OFF_W   = OFF_ST + SZ_ST;
constexpr size_t OFF_CT  = OFF_W + SZ_P;
constexpr size_t OFF_WLC = OFF_CT + SZ_P;
constexpr size_t OFF_EWT = OFF_WLC + SZ_P;
constexpr size_t SZ_EWT  = (size_t)DIN * H_;
constexpr size_t OFF_WOB = OFF_EWT + SZ_EWT;           // bf16 Wo: NL*512*256 -> /2 slots
constexpr size_t SZ_WOB  = (size_t)NL_ * 2 * H_ * H_ / 2;
constexpr size_t OFF_SEG = OFF_WOB + SZ_WOB;           // f32 segbuf B*SEG*H*N2*2

typedef short bf16x8 __attribute__((ext_vector_type(8)));
typedef float f32x4  __attribute__((ext_vector_type(4)));

// ---------------------------------------------------------------------------
// per-layer SSM parameters: w = exp(dt*A), Ct2 = 2*C*(w-1)/A, wLc = w^LC
__global__ __launch_bounds__(256) void k_params(
    const float* __restrict__ log_dt, const float* __restrict__ log_A_re,
    const float* __restrict__ A_im, const float* __restrict__ C_re,
    const float* __restrict__ C_im, float* __restrict__ ws)
{
    int idx = blockIdx.x * 256 + threadIdx.x;     // over NL*H*N2
    if (idx >= NL_ * H_ * N2_) return;
    int i  = idx / (H_ * N2_);
    int hh = (idx / N2_) % H_;
    float dt  = expf(log_dt[i * H_ + hh]);
    float Are = -expf(log_A_re[idx]);
    float Aim = A_im[idx];
    float zre = dt * Are, zim = dt * Aim;
    float er  = expf(zre);
    float wre = er * cosf(zim), wim = er * sinf(zim);
    float d   = Are * Are + Aim * Aim;
    float nre = wre - 1.f, nim = wim;
    float qre = (nre * Are + nim * Aim) / d;
    float qim = (nim * Are - nre * Aim) / d;
    float cr = C_re[idx], ci = C_im[idx];
    float ctre = cr * qre - ci * qim;
    float ctim = cr * qim + ci * qre;
    float er2 = expf(zre * (float)LC);
    float wlre = er2 * cosf(zim * (float)LC);
    float wlim = er2 * sinf(zim * (float)LC);
    ((float2*)(ws + OFF_W))[idx]   = make_float2(wre, wim);
    ((float2*)(ws + OFF_CT))[idx]  = make_float2(2.f * ctre, 2.f * ctim);
    ((float2*)(ws + OFF_WLC))[idx] = make_float2(wlre, wlim);
}

// ---------------------------------------------------------------------------
__global__ __launch_bounds__(256) void k_transpose(const float* __restrict__ src,
    float* __restrict__ dst, int R, int Cc)   // src R x Cc -> dst Cc x R
{
    __shared__ float t[32][33];
    int x = blockIdx.x * 32 + threadIdx.x;
    #pragma unroll
    for (int i = 0; i < 4; i++) {
        int yy = blockIdx.y * 32 + threadIdx.y + i * 8;
        if (x < Cc && yy < R) t[threadIdx.y + i * 8][threadIdx.x] = src[(size_t)yy * Cc + x];
    }
    __syncthreads();
    int xo = blockIdx.y * 32 + threadIdx.x;
    #pragma unroll
    for (int i = 0; i < 4; i++) {
        int yo = blockIdx.x * 32 + threadIdx.y + i * 8;
        if (xo < R && yo < Cc) dst[(size_t)yo * R + xo] = t[threadIdx.x][threadIdx.y + i * 8];
    }
}

// ---------------------------------------------------------------------------
// fp32 -> bf16 convert (Wo weights), 4 elements/thread
__global__ __launch_bounds__(256) void k_wcvt(const float* __restrict__ src,
    __hip_bfloat16* __restrict__ dst, int n4)
{
    int i = blockIdx.x * 256 + threadIdx.x;
    if (i >= n4) return;
    float4 v = ((const float4*)src)[i];
    union { __hip_bfloat16 b[4]; uint2 u; } o;
    o.b[0] = __float2bfloat16(v.x); o.b[1] = __float2bfloat16(v.y);
    o.b[2] = __float2bfloat16(v.z); o.b[3] = __float2bfloat16(v.w);
    ((uint2*)dst)[i] = o.u;
}

// ---------------------------------------------------------------------------
// encoder: h[M,256] = x[M,64] @ encWT[64,256] + enc_b
__global__ __launch_bounds__(256) void k_encoder(const float* __restrict__ x,
    const float* __restrict__ encWT, const float* __restrict__ enc_b,
    float* __restrict__ h)
{
    __shared__ float As[DIN][36];
    __shared__ float Bs[32][256];
    int m0 = blockIdx.x * 32;
    int tid = threadIdx.x;
    const float4* x4 = (const float4*)x;
    #pragma unroll
    for (int q = 0; q < 2; q++) {
        int f = tid * 2 + q;
        int row = f >> 4, kq = f & 15;
        float4 v = x4[(size_t)(m0 + row) * 16 + kq];
        As[kq * 4 + 0][row] = v.x; As[kq * 4 + 1][row] = v.y;
        As[kq * 4 + 2][row] = v.z; As[kq * 4 + 3][row] = v.w;
    }
    int tx = tid & 31, ty = tid >> 5;
    float acc[4][8];
    #pragma unroll
    for (int p = 0; p < 4; p++)
        #pragma unroll
        for (int j = 0; j < 8; j++) acc[p][j] = 0.f;
    const float4* w4 = (const float4*)encWT;
    for (int ks = 0; ks < 2; ks++) {
        __syncthreads();
        #pragma unroll
        for (int it = 0; it < 8; it++) {
            int q = it * 256 + tid;
            ((float4*)Bs)[q] = w4[ks * 2048 + q];
        }
        __syncthreads();
        #pragma unroll 8
        for (int kk = 0; kk < 32; kk++) {
            int k = ks * 32 + kk;
            float4 a  = *(const float4*)&As[k][ty * 4];
            float4 b0 = *(const float4*)&Bs[kk][tx * 4];
            float4 b1 = *(const float4*)&Bs[kk][128 + tx * 4];
            float av[4] = {a.x, a.y, a.z, a.w};
            float bv[8] = {b0.x, b0.y, b0.z, b0.w, b1.x, b1.y, b1.z, b1.w};
            #pragma unroll
            for (int p = 0; p < 4; p++)
                #pragma unroll
                for (int j = 0; j < 8; j++)
                    acc[p][j] = fmaf(av[p], bv[j], acc[p][j]);
        }
    }
    float4 eb0 = *(const float4*)&enc_b[tx * 4];
    float4 eb1 = *(const float4*)&enc_b[128 + tx * 4];
    float ebv[8] = {eb0.x, eb0.y, eb0.z, eb0.w, eb1.x, eb1.y, eb1.z, eb1.w};
    float4* h4 = (float4*)h;
    #pragma unroll
    for (int p = 0; p < 4; p++) {
        size_t pos = m0 + ty * 4 + p;
        float4 o0 = make_float4(acc[p][0] + ebv[0], acc[p][1] + ebv[1],
                                acc[p][2] + ebv[2], acc[p][3] + ebv[3]);
        float4 o1 = make_float4(acc[p][4] + ebv[4], acc[p][5] + ebv[5],
                                acc[p][6] + ebv[6], acc[p][7] + ebv[7]);
        h4[pos * 64 + tx]      = o0;
        h4[pos * 64 + 32 + tx] = o1;
    }
}

// ---------------------------------------------------------------------------
// pass1: per-chunk local final state (zero init). thread = (b,c,h,n)
__global__ __launch_bounds__(256) void k_chunkstate(const float* __restrict__ hin,
    const float* __restrict__ ws, int layer, float* __restrict__ st)
{
    int bid = blockIdx.x;
    int hg = bid & 31;
    int c  = (bid >> 5) & (CHK - 1);
    int b  = bid >> 12;
    int n  = threadIdx.x & 31;
    int hh = hg * 8 + (threadIdx.x >> 5);
    float2 w = ((const float2*)(ws + OFF_W))[(size_t)layer * H_ * N2_ + hh * N2_ + n];
    float sre = 0.f, sim = 0.f;
    const float* xp = hin + ((size_t)b * L_ + c * LC) * H_ + hh;
    #pragma unroll 4
    for (int t = 0; t < LC; t++) {
        float xv = xp[t * H_];
        float tre = fmaf(w.x, sre, xv);
        tre = fmaf(-w.y, sim, tre);
        float tim = fmaf(w.x, sim, w.y * sre);
        sre = tre; sim = tim;
    }
    ((float2*)st)[((size_t)(b * CHK + c) * H_ + hh) * N2_ + n] = make_float2(sre, sim);
}

// ---------------------------------------------------------------------------
// scan phase a: per-segment local compose. thread = (b, hh, seg, n)
__global__ __launch_bounds__(256) void k_scan_a(const float* __restrict__ ws, int layer,
    const float* __restrict__ st, float* __restrict__ seg)
{
    int g = blockIdx.x * 256 + threadIdx.x;   // B*H*SEG*N2 = 262144
    int n  = g & 31;
    int s  = (g >> 5) & (SEG - 1);
    int hh = (g >> 8) & (H_ - 1);
    int b  = g >> 16;
    float2 wl = ((const float2*)(ws + OFF_WLC))[(size_t)layer * H_ * N2_ + hh * N2_ + n];
    const float2* stp = (const float2*)st;
    float ar = 0.f, ai = 0.f;
    #pragma unroll
    for (int j = 0; j < SEGC; j++) {
        size_t idx = ((size_t)(b * CHK + s * SEGC + j) * H_ + hh) * N2_ + n;
        float2 v = stp[idx];
        float tr = fmaf(wl.x, ar, v.x); tr = fmaf(-wl.y, ai, tr);
        float ti = fmaf(wl.x, ai, v.y); ti = fmaf(wl.y, ar, ti);
        ar = tr; ai = ti;
    }
    ((float2*)seg)[((size_t)(b * SEG + s) * H_ + hh) * N2_ + n] = make_float2(ar, ai);
}

// ---------------------------------------------------------------------------
// scan phase b: scan 8 segments; seg[s] becomes incoming state of segment s
__global__ __launch_bounds__(256) void k_scan_b(const float* __restrict__ ws, int layer,
    float* __restrict__ seg)
{
    int g = blockIdx.x * 256 + threadIdx.x;   // B*H*N2 = 32768
    int n  = g & 31;
    int hh = (g >> 5) & (H_ - 1);
    int b  = g >> 13;
    float2 wl = ((const float2*)(ws + OFF_WLC))[(size_t)layer * H_ * N2_ + hh * N2_ + n];
    float wr = wl.x, wi = wl.y;
    #pragma unroll
    for (int q = 0; q < 4; q++) {             // wLc^16
        float nr = wr * wr - wi * wi;
        float ni = 2.f * wr * wi;
        wr = nr; wi = ni;
    }
    float2* sp = (float2*)seg;
    float ar = 0.f, ai = 0.f;
    #pragma unroll
    for (int s = 0; s < SEG; s++) {
        size_t idx = ((size_t)(b * SEG + s) * H_ + hh) * N2_ + n;
        float2 v = sp[idx];
        sp[idx] = make_float2(ar, ai);
        float tr = fmaf(wr, ar, v.x); tr = fmaf(-wi, ai, tr);
        float ti = fmaf(wr, ai, v.y); ti = fmaf(wi, ar, ti);
        ar = tr; ai = ti;
    }
}

// ---------------------------------------------------------------------------
// scan phase c: expand within segment; st[c] becomes incoming state (in-place)
__global__ __launch_bounds__(256) void k_scan_c(const float* __restrict__ ws, int layer,
    const float* __restrict__ seg, float* __restrict__ st)
{
    int g = blockIdx.x * 256 + threadIdx.x;   // B*H*SEG*N2 = 262144
    int n  = g & 31;
    int s  = (g >> 5) & (SEG - 1);
    int hh = (g >> 8) & (H_ - 1);
    int b  = g >> 16;
    float2 wl = ((const float2*)(ws + OFF_WLC))[(size_t)layer * H_ * N2_ + hh * N2_ + n];
    float2 in0 = ((const float2*)seg)[((size_t)(b * SEG + s) * H_ + hh) * N2_ + n];
    float ar = in0.x, ai = in0.y;
    float2* stp = (float2*)st;
    #pragma unroll
    for (int j = 0; j < SEGC; j++) {
        size_t idx = ((size_t)(b * CHK + s * SEGC + j) * H_ + hh) * N2_ + n;
        float2 v = stp[idx];
        stp[idx] = make_float2(ar, ai);
        float tr = fmaf(wl.x, ar, v.x); tr = fmaf(-wl.y, ai, tr);
        float ti = fmaf(wl.x, ai, v.y); ti = fmaf(wl.y, ar, ti);
        ar = tr; ai = ti;
    }
}

// ---------------------------------------------------------------------------
// pass3: replay with carries; y = gelu(conv + D*u) -> bf16.
// thread = (channel, n-octet): 8 states each, 4-lane shuffle reduce.
#define STEP(n, A) { \
    float tre = fmaf(wre[n], sre[n], xv); \
    tre = fmaf(-wim[n], sim[n], tre); \
    float tim = fmaf(wre[n], sim[n], wim[n] * sre[n]); \
    sre[n] = tre; sim[n] = tim; \
    A = fmaf(cre_[n], tre, A); \
    A = fmaf(-cim_[n], tim, A); }

__global__ __launch_bounds__(256) void k_conv(const float* __restrict__ hin,
    const float* __restrict__ ws, int layer, const float* __restrict__ Dp,
    const float* __restrict__ st, __hip_bfloat16* __restrict__ yout)
{
    int blk = blockIdx.x;                 // b*(CHK*4) + c*4 + hb
    int hb = blk & 3;
    int c  = (blk >> 2) & (CHK - 1);
    int b  = blk >> 9;
    int tid = threadIdx.x;
    int ng = tid & 3;
    int hl = tid >> 2;
    int hh = hb * 64 + hl;
    int n0 = ng * 8;
    float wre[8], wim[8], cre_[8], cim_[8], sre[8], sim[8];
    const float4* w4 = (const float4*)(ws + OFF_W  + ((size_t)layer * H_ * N2_ + hh * N2_ + n0) * 2);
    const float4* c4 = (const float4*)(ws + OFF_CT + ((size_t)layer * H_ * N2_ + hh * N2_ + n0) * 2);
    const float4* s4 = (const float4*)(st + ((size_t)(b * CHK + c) * H_ + hh) * N2_ * 2 + n0 * 2);
    #pragma unroll
    for (int j = 0; j < 4; j++) {
        float4 v = w4[j]; wre[2*j] = v.x; wim[2*j] = v.y; wre[2*j+1] = v.z; wim[2*j+1] = v.w;
        float4 u = c4[j]; cre_[2*j] = u.x; cim_[2*j] = u.y; cre_[2*j+1] = u.z; cim_[2*j+1] = u.w;
        float4 s = s4[j]; sre[2*j] = s.x; sim[2*j] = s.y; sre[2*j+1] = s.z; sim[2*j+1] = s.w;
    }
    float Dh = Dp[layer * H_ + hh];
    size_t base = ((size_t)b * L_ + c * LC) * H_ + hh;
    const float* xp = hin + base;
    __hip_bfloat16* yp = yout + base;
    #pragma unroll 1
    for (int t = 0; t < LC; t++) {
        float xv = xp[t * H_];
        float a0 = 0.f, a1 = 0.f;
        STEP(0, a0) STEP(1, a1) STEP(2, a0) STEP(3, a1)
        STEP(4, a0) STEP(5, a1) STEP(6, a0) STEP(7, a1)
        float a = a0 + a1;
        a += __shfl_xor(a, 1);
        a += __shfl_xor(a, 2);
        float v = fmaf(Dh, xv, a);
        float g = 0.7978845608028654f * fmaf(0.044715f * v, v * v, v);
        float yv = v / (1.f + __expf(-2.f * g));
        if (ng == 0) yp[t * H_] = __float2bfloat16(yv);
    }
}
#undef STEP

// ---------------------------------------------------------------------------
// fused MFMA: u = y @ Wo^T + bo ; z = u[:256]*sigmoid(u[256:]) ; h = LN(z+h)
__global__ __launch_bounds__(256) void k_glu_mfma(
    const __hip_bfloat16* __restrict__ yb,   // [M,256] bf16 (k contiguous)
    float* __restrict__ h,                   // [M,256] f32 in/out
    const __hip_bfloat16* __restrict__ wob,  // [512,256] bf16 (n-major, k contiguous)
    const float* __restrict__ bo, const float* __restrict__ lnw,
    const float* __restrict__ lnb)
{
    int tid = threadIdx.x;
    int w   = tid >> 6;
    int l   = tid & 63;
    int l15 = l & 15, l4 = l >> 4;
    int m0  = blockIdx.x * 64;
    int nv  = w * 64;
    f32x4 accv[4][4], accg[4][4];
    #pragma unroll
    for (int mi = 0; mi < 4; mi++)
        #pragma unroll
        for (int nj = 0; nj < 4; nj++) { accv[mi][nj] = (f32x4)0.f; accg[mi][nj] = (f32x4)0.f; }

    #pragma unroll 1
    for (int ks = 0; ks < 8; ks++) {
        int k0 = ks * 32 + l4 * 8;
        bf16x8 a[4];
        #pragma unroll
        for (int mi = 0; mi < 4; mi++)
            a[mi] = *(const bf16x8*)(yb + (size_t)(m0 + mi * 16 + l15) * H_ + k0);
        #pragma unroll
        for (int nj = 0; nj < 4; nj++) {
            bf16x8 bv = *(const bf16x8*)(wob + (size_t)(nv + nj * 16 + l15) * H_ + k0);
            bf16x8 bg = *(const bf16x8*)(wob + (size_t)(256 + nv + nj * 16 + l15) * H_ + k0);
            #pragma unroll
            for (int mi = 0; mi < 4; mi++) {
                accv[mi][nj] = __builtin_amdgcn_mfma_f32_16x16x32_bf16(a[mi], bv, accv[mi][nj], 0, 0, 0);
                accg[mi][nj] = __builtin_amdgcn_mfma_f32_16x16x32_bf16(a[mi], bg, accg[mi][nj], 0, 0, 0);
            }
        }
    }

    float bov[4], bog[4], lw[4], lb[4];
    #pragma unroll
    for (int nj = 0; nj < 4; nj++) {
        int cn = nv + nj * 16 + l15;
        bov[nj] = bo[cn]; bog[nj] = bo[256 + cn];
        lw[nj] = lnw[cn]; lb[nj] = lnb[cn];
    }
    __shared__ float red[4][64][2];
    #pragma unroll
    for (int mi = 0; mi < 4; mi++) {
        #pragma unroll
        for (int r = 0; r < 4; r++) {
            int lr = mi * 16 + l4 * 4 + r;
            size_t row = (size_t)(m0 + lr);
            float s = 0.f, ss = 0.f;
            #pragma unroll
            for (int nj = 0; nj < 4; nj++) {
                float uv = accv[mi][nj][r] + bov[nj];
                float ug = accg[mi][nj][r] + bog[nj];
                float z  = uv / (1.f + __expf(-ug));
                float v  = z + h[row * H_ + nv + nj * 16 + l15];
                accv[mi][nj][r] = v;
                s += v; ss += v * v;
            }
            #pragma unroll
            for (int off = 1; off < 16; off <<= 1) {
                s  += __shfl_xor(s, off);
                ss += __shfl_xor(ss, off);
            }
            if (l15 == 0) { red[w][lr][0] = s; red[w][lr][1] = ss; }
        }
    }
    __syncthreads();
    #pragma unroll
    for (int mi = 0; mi < 4; mi++) {
        #pragma unroll
        for (int r = 0; r < 4; r++) {
            int lr = mi * 16 + l4 * 4 + r;
            size_t row = (size_t)(m0 + lr);
            float s  = red[0][lr][0] + red[1][lr][0] + red[2][lr][0] + red[3][lr][0];
            float ss = red[0][lr][1] + red[1][lr][1] + red[2][lr][1] + red[3][lr][1];
            float mu = s * (1.f / 256.f);
            float var = ss * (1.f / 256.f) - mu * mu;
            float rstd = rsqrtf(var + 1e-5f);
            #pragma unroll
            for (int nj = 0; nj < 4; nj++)
                h[row * H_ + nv + nj * 16 + l15] =
                    (accv[mi][nj][r] - mu) * rstd * lw[nj] + lb[nj];
        }
    }
}

// ---------------------------------------------------------------------------
__global__ __launch_bounds__(256) void k_decoder(const float* __restrict__ h,
    const float* __restrict__ out_W, const float* __restrict__ out_b,
    float* __restrict__ out)
{
    __shared__ float hs[16][260];
    __shared__ float wl[10][260];
    int p0 = blockIdx.x * 16;
    int tid = threadIdx.x;
    const float4* h4 = (const float4*)h;
    #pragma unroll
    for (int it = 0; it < 4; it++) {
        int q = it * 256 + tid;
        int r = q >> 6, k4 = q & 63;
        float4 v = h4[(size_t)(p0 + r) * 64 + k4];
        *(float4*)&hs[r][k4 * 4] = v;
    }
    for (int q = tid; q < 640; q += 256) {
        int r = q / 64, k4 = q % 64;
        *(float4*)&wl[r][k4 * 4] = ((const float4*)out_W)[q];
    }
    __syncthreads();
    int slot = tid & 15, pl = tid >> 4;
    if (slot < DOUT) {
        float a0 = 0.f, a1 = 0.f, a2 = 0.f, a3 = 0.f;
        #pragma unroll 8
        for (int k = 0; k < 256; k += 4) {
            a0 = fmaf(hs[pl][k + 0], wl[slot][k + 0], a0);
            a1 = fmaf(hs[pl][k + 1], wl[slot][k + 1], a1);
            a2 = fmaf(hs[pl][k + 2], wl[slot][k + 2], a2);
            a3 = fmaf(hs[pl][k + 3], wl[slot][k + 3], a3);
        }
        out[(size_t)(p0 + pl) * DOUT + slot] = (a0 + a1) + (a2 + a3) + out_b[slot];
    }
}

// ---------------------------------------------------------------------------
extern "C" void kernel_launch(void* const* d_in, const int* in_sizes, int n_in,
                              void* d_out, int out_size, void* d_ws, size_t ws_size,
                              hipStream_t stream)
{
    (void)in_sizes; (void)n_in; (void)out_size; (void)ws_size;
    const float* x        = (const float*)d_in[0];
    const float* enc_W    = (const float*)d_in[1];
    const float* enc_b    = (const float*)d_in[2];
    const float* log_dt   = (const float*)d_in[3];
    const float* log_A_re = (const float*)d_in[4];
    const float* A_im     = (const float*)d_in[5];
    const float* C_re     = (const float*)d_in[6];
    const float* C_im     = (const float*)d_in[7];
    const float* Dp       = (const float*)d_in[8];
    const float* Wo       = (const float*)d_in[9];
    const float* bo       = (const float*)d_in[10];
    const float* lnw      = (const float*)d_in[11];
    const float* lnb      = (const float*)d_in[12];
    const float* out_W    = (const float*)d_in[13];
    const float* out_b    = (const float*)d_in[14];
    float* ws = (float*)d_ws;
    float* h  = ws + OFF_H;
    __hip_bfloat16* y = (__hip_bfloat16*)(ws + OFF_Y);
    float* st = ws + OFF_ST;
    float* segb = ws + OFF_SEG;
    __hip_bfloat16* wob = (__hip_bfloat16*)(ws + OFF_WOB);

    k_params<<<NL_ * H_ * N2_ / 256, 256, 0, stream>>>(log_dt, log_A_re, A_im, C_re, C_im, ws);
    dim3 tb(32, 8);
    k_transpose<<<dim3(DIN / 32, H_ / 32), tb, 0, stream>>>(enc_W, ws + OFF_EWT, H_, DIN);
    k_wcvt<<<(NL_ * 2 * H_ * H_ / 4 + 255) / 256, 256, 0, stream>>>(Wo, wob, NL_ * 2 * H_ * H_ / 4);
    k_encoder<<<M_ / 32, 256, 0, stream>>>(x, ws + OFF_EWT, enc_b, h);
    for (int i = 0; i < NL_; i++) {
        k_chunkstate<<<B_ * CHK * (H_ / 8), 256, 0, stream>>>(h, ws, i, st);
        k_scan_a<<<B_ * H_ * SEG * N2_ / 256, 256, 0, stream>>>(ws, i, st, segb);
        k_scan_b<<<B_ * H_ * N2_ / 256, 256, 0, stream>>>(ws, i, segb);
        k_scan_c<<<B_ * H_ * SEG * N2_ / 256, 256, 0, stream>>>(ws, i, segb, st);
        k_conv<<<B_ * CHK * 4, 256, 0, stream>>>(h, ws, i, Dp, st, y);
        k_glu_mfma<<<M_ / 64, 256, 0, stream>>>(y, h,
            wob + (size_t)i * 2 * H_ * H_, bo + (size_t)i * 2 * H_,
            lnw + (size_t)i * H_, lnb + (size_t)i * H_);
    }
    k_decoder<<<M_ / 16, 256, 0, stream>>>(h, out_W, out_b, (float*)d_out);
}

// Round 4
// 557.622 us; speedup vs baseline: 1.4586x; 1.4586x over previous
//
#include <hip/hip_runtime.h>
#include <hip/hip_bf16.h>

// ---------------------------------------------------------------------------
// S4D stack, MFMA everywhere:
// encoder GEMM -> 4x[ h->cm transpose; per-channel MFMA GEMMs for chunk-states
//   and Toeplitz conv (+carry); tiny segmented scan; cm->pm transpose;
//   GLU MFMA GEMM + LN ] -> decoder.
// h fp32 position-major; u/y/st bf16 channel-major; ws ~94 MB.
// ---------------------------------------------------------------------------

constexpr int B_ = 4, L_ = 8192, DIN = 64, H_ = 256, N2_ = 32, NL_ = 4, DOUT = 10;
constexpr int LC = 64, CHK = L_ / LC;     // 128 chunks/batch, 512 global chunks
constexpr int GCH = B_ * CHK;             // 512
constexpr int M_ = B_ * L_;               // 32768 positions
constexpr int SEG = 8, SEGC = CHK / SEG;  // 8 segments x 16 chunks

// ws layout in float slots
constexpr size_t OFF_H    = 0;                         // f32 [M][H] 8388608
constexpr size_t OFF_WOB  = 8388608;                   // bf16 Wo NL*512*256 -> 262144
constexpr size_t OFF_PW   = 8650752;                   // f32 w pairs 65536
constexpr size_t OFF_PCT  = 8716288;                   // f32 Ct2 pairs 65536
constexpr size_t OFF_PWLC = 8781824;                   // f32 w^64 pairs 65536
constexpr size_t OFF_PZ   = 8847360;                   // f32 z=dtA pairs 65536
constexpr size_t OFF_EWT  = 8912896;                   // f32 enc W^T 16384
constexpr size_t OFF_UCM  = 8929280;                   // bf16 [H][M] u cm / y pm alias
constexpr size_t OFF_YCM  = 13123584;                  // bf16 [H][M] y cm
constexpr size_t OFF_ST   = 17317888;                  // bf16 [H][GCH][64]
constexpr size_t OFF_SEG  = 21512192;                  // f32 [H][B][SEG][64]
constexpr size_t OFF_MT   = 22036480;                  // bf16 Ttr [H][64][64]
constexpr size_t OFF_MW   = 22560768;                  // bf16 Wtr [H][64][64]
constexpr size_t OFF_MV   = 23085056;                  // bf16 Vtr [H][64][64]
// end 23609344 slots = 94.4 MB

typedef short bf16x8 __attribute__((ext_vector_type(8)));
typedef short short8 __attribute__((ext_vector_type(8)));
typedef short short4v __attribute__((ext_vector_type(4)));
typedef float f32x4  __attribute__((ext_vector_type(4)));

// ---------------------------------------------------------------------------
// per-layer SSM params: w=exp(dtA), Ct2=2C(w-1)/A, wLc=w^64, z=dtA
__global__ __launch_bounds__(256) void k_params(
    const float* __restrict__ log_dt, const float* __restrict__ log_A_re,
    const float* __restrict__ A_im, const float* __restrict__ C_re,
    const float* __restrict__ C_im, float* __restrict__ ws)
{
    int idx = blockIdx.x * 256 + threadIdx.x;     // over NL*H*N2
    if (idx >= NL_ * H_ * N2_) return;
    int i  = idx / (H_ * N2_);
    int hh = (idx / N2_) % H_;
    float dt  = expf(log_dt[i * H_ + hh]);
    float Are = -expf(log_A_re[idx]);
    float Aim = A_im[idx];
    float zre = dt * Are, zim = dt * Aim;
    float er  = expf(zre);
    float wre = er * cosf(zim), wim = er * sinf(zim);
    float d   = Are * Are + Aim * Aim;
    float nre = wre - 1.f, nim = wim;
    float qre = (nre * Are + nim * Aim) / d;
    float qim = (nim * Are - nre * Aim) / d;
    float cr = C_re[idx], ci = C_im[idx];
    float ctre = cr * qre - ci * qim;
    float ctim = cr * qim + ci * qre;
    float er2 = expf(zre * (float)LC);
    float wlre = er2 * cosf(zim * (float)LC);
    float wlim = er2 * sinf(zim * (float)LC);
    ((float2*)(ws + OFF_PW))[idx]   = make_float2(wre, wim);
    ((float2*)(ws + OFF_PCT))[idx]  = make_float2(2.f * ctre, 2.f * ctim);
    ((float2*)(ws + OFF_PWLC))[idx] = make_float2(wlre, wlim);
    ((float2*)(ws + OFF_PZ))[idx]   = make_float2(zre, zim);
}

// ---------------------------------------------------------------------------
// build per-channel bf16 matrices for layer: Ttr[t][j]=k[t-j], Wtr[m][j],
// Vtr[t][m].  block = channel.
__global__ __launch_bounds__(256) void k_mats(const float* __restrict__ ws,
    int layer, __hip_bfloat16* __restrict__ mt, __hip_bfloat16* __restrict__ mw,
    __hip_bfloat16* __restrict__ mv)
{
    int h = blockIdx.x, tid = threadIdx.x;
    __shared__ float zre[32], zim[32], ctr[32], cti[32], kv[64];
    if (tid < 32) {
        float2 z = ((const float2*)(ws + OFF_PZ))[(size_t)layer*H_*N2_ + h*N2_ + tid];
        float2 c = ((const float2*)(ws + OFF_PCT))[(size_t)layer*H_*N2_ + h*N2_ + tid];
        zre[tid] = z.x; zim[tid] = z.y; ctr[tid] = c.x; cti[tid] = c.y;
    }
    __syncthreads();
    if (tid < 64) {                        // k[d] = Re sum_n Ct2 w^d
        float d = (float)tid, acc = 0.f;
        for (int n = 0; n < 32; n++) {
            float er = expf(zre[n] * d);
            float co = cosf(zim[n] * d), si = sinf(zim[n] * d);
            acc += er * (ctr[n] * co - cti[n] * si);
        }
        kv[tid] = acc;
    }
    __syncthreads();
    {   // Ttr
        int t = tid >> 2, j0 = (tid & 3) * 16;
        alignas(16) __hip_bfloat16 row[16];
        #pragma unroll
        for (int jj = 0; jj < 16; jj++) {
            int j = j0 + jj;
            row[jj] = __float2bfloat16(j <= t ? kv[t - j] : 0.f);
        }
        *(short8*)(mt + (size_t)h*4096 + t*64 + j0)     = *(short8*)&row[0];
        *(short8*)(mt + (size_t)h*4096 + t*64 + j0 + 8) = *(short8*)&row[8];
    }
    {   // Wtr[2n][j]=Re w^{63-j}, [2n+1][j]=Im w^{63-j}
        int n = tid >> 3, j0 = (tid & 7) * 8;
        alignas(16) __hip_bfloat16 rre[8], rim[8];
        #pragma unroll
        for (int jj = 0; jj < 8; jj++) {
            float e = (float)(63 - (j0 + jj));
            float er = expf(zre[n] * e);
            rre[jj] = __float2bfloat16(er * cosf(zim[n] * e));
            rim[jj] = __float2bfloat16(er * sinf(zim[n] * e));
        }
        *(short8*)(mw + (size_t)h*4096 + (2*n)*64 + j0)   = *(short8*)&rre[0];
        *(short8*)(mw + (size_t)h*4096 + (2*n+1)*64 + j0) = *(short8*)&rim[0];
    }
    {   // Vtr[t][2n]=Re(Ct2 w^{t+1}), [2n+1]=-Im(Ct2 w^{t+1})
        int t = tid >> 2, n0 = (tid & 3) * 8;
        float e = (float)(t + 1);
        alignas(16) __hip_bfloat16 row[16];
        #pragma unroll
        for (int k = 0; k < 8; k++) {
            int n = n0 + k;
            float er = expf(zre[n] * e);
            float wr = er * cosf(zim[n] * e), wi = er * sinf(zim[n] * e);
            row[2*k]   = __float2bfloat16(ctr[n]*wr - cti[n]*wi);
            row[2*k+1] = __float2bfloat16(-(ctr[n]*wi + cti[n]*wr));
        }
        *(short8*)(mv + (size_t)h*4096 + t*64 + 2*n0)     = *(short8*)&row[0];
        *(short8*)(mv + (size_t)h*4096 + t*64 + 2*n0 + 8) = *(short8*)&row[8];
    }
}

// ---------------------------------------------------------------------------
__global__ __launch_bounds__(256) void k_transpose(const float* __restrict__ src,
    float* __restrict__ dst, int R, int Cc)   // src R x Cc -> dst Cc x R
{
    __shared__ float t[32][33];
    int x = blockIdx.x * 32 + threadIdx.x;
    #pragma unroll
    for (int i = 0; i < 4; i++) {
        int yy = blockIdx.y * 32 + threadIdx.y + i * 8;
        if (x < Cc && yy < R) t[threadIdx.y + i * 8][threadIdx.x] = src[(size_t)yy * Cc + x];
    }
    __syncthreads();
    int xo = blockIdx.y * 32 + threadIdx.x;
    #pragma unroll
    for (int i = 0; i < 4; i++) {
        int yo = blockIdx.x * 32 + threadIdx.y + i * 8;
        if (xo < R && yo < Cc) dst[(size_t)yo * R + xo] = t[threadIdx.x][threadIdx.y + i * 8];
    }
}

// ---------------------------------------------------------------------------
__global__ __launch_bounds__(256) void k_wcvt(const float* __restrict__ src,
    __hip_bfloat16* __restrict__ dst, int n4)
{
    int i = blockIdx.x * 256 + threadIdx.x;
    if (i >= n4) return;
    float4 v = ((const float4*)src)[i];
    union { __hip_bfloat16 b[4]; uint2 u; } o;
    o.b[0] = __float2bfloat16(v.x); o.b[1] = __float2bfloat16(v.y);
    o.b[2] = __float2bfloat16(v.z); o.b[3] = __float2bfloat16(v.w);
    ((uint2*)dst)[i] = o.u;
}

// ---------------------------------------------------------------------------
// encoder: h[M,256] = x[M,64] @ encWT[64,256] + enc_b
__global__ __launch_bounds__(256) void k_encoder(const float* __restrict__ x,
    const float* __restrict__ encWT, const float* __restrict__ enc_b,
    float* __restrict__ h)
{
    __shared__ float As[DIN][36];
    __shared__ float Bs[32][256];
    int m0 = blockIdx.x * 32;
    int tid = threadIdx.x;
    const float4* x4 = (const float4*)x;
    #pragma unroll
    for (int q = 0; q < 2; q++) {
        int f = tid * 2 + q;
        int row = f >> 4, kq = f & 15;
        float4 v = x4[(size_t)(m0 + row) * 16 + kq];
        As[kq * 4 + 0][row] = v.x; As[kq * 4 + 1][row] = v.y;
        As[kq * 4 + 2][row] = v.z; As[kq * 4 + 3][row] = v.w;
    }
    int tx = tid & 31, ty = tid >> 5;
    float acc[4][8];
    #pragma unroll
    for (int p = 0; p < 4; p++)
        #pragma unroll
        for (int j = 0; j < 8; j++) acc[p][j] = 0.f;
    const float4* w4 = (const float4*)encWT;
    for (int ks = 0; ks < 2; ks++) {
        __syncthreads();
        #pragma unroll
        for (int it = 0; it < 8; it++) {
            int q = it * 256 + tid;
            ((float4*)Bs)[q] = w4[ks * 2048 + q];
        }
        __syncthreads();
        #pragma unroll 8
        for (int kk = 0; kk < 32; kk++) {
            int k = ks * 32 + kk;
            float4 a  = *(const float4*)&As[k][ty * 4];
            float4 b0 = *(const float4*)&Bs[kk][tx * 4];
            float4 b1 = *(const float4*)&Bs[kk][128 + tx * 4];
            float av[4] = {a.x, a.y, a.z, a.w};
            float bv[8] = {b0.x, b0.y, b0.z, b0.w, b1.x, b1.y, b1.z, b1.w};
            #pragma unroll
            for (int p = 0; p < 4; p++)
                #pragma unroll
                for (int j = 0; j < 8; j++)
                    acc[p][j] = fmaf(av[p], bv[j], acc[p][j]);
        }
    }
    float4 eb0 = *(const float4*)&enc_b[tx * 4];
    float4 eb1 = *(const float4*)&enc_b[128 + tx * 4];
    float ebv[8] = {eb0.x, eb0.y, eb0.z, eb0.w, eb1.x, eb1.y, eb1.z, eb1.w};
    float4* h4 = (float4*)h;
    #pragma unroll
    for (int p = 0; p < 4; p++) {
        size_t pos = m0 + ty * 4 + p;
        float4 o0 = make_float4(acc[p][0] + ebv[0], acc[p][1] + ebv[1],
                                acc[p][2] + ebv[2], acc[p][3] + ebv[3]);
        float4 o1 = make_float4(acc[p][4] + ebv[4], acc[p][5] + ebv[5],
                                acc[p][6] + ebv[6], acc[p][7] + ebv[7]);
        h4[pos * 64 + tx]      = o0;
        h4[pos * 64 + 32 + tx] = o1;
    }
}

// ---------------------------------------------------------------------------
// h (f32 [M][H]) -> u_cm (bf16 [H][M]), 64x64 tiles via LDS
__global__ __launch_bounds__(256) void k_h2cm(const float* __restrict__ h,
    __hip_bfloat16* __restrict__ ucm)
{
    __shared__ float lds[64][65];
    int pos0 = blockIdx.x * 64, ch0 = blockIdx.y * 64;
    int tid = threadIdx.x;
    int p = tid >> 4, c4 = (tid & 15) * 4;
    #pragma unroll
    for (int pp = 0; pp < 4; pp++) {
        float4 v = *(const float4*)(h + (size_t)(pos0 + p + pp * 16) * H_ + ch0 + c4);
        lds[p + pp*16][c4]   = v.x; lds[p + pp*16][c4+1] = v.y;
        lds[p + pp*16][c4+2] = v.z; lds[p + pp*16][c4+3] = v.w;
    }
    __syncthreads();
    int ch = tid >> 2, p0 = (tid & 3) * 16;
    alignas(16) __hip_bfloat16 row[16];
    #pragma unroll
    for (int k = 0; k < 16; k++) row[k] = __float2bfloat16(lds[p0 + k][ch]);
    size_t base = (size_t)(ch0 + ch) * M_ + pos0 + p0;
    *(short8*)(ucm + base)     = *(short8*)&row[0];
    *(short8*)(ucm + base + 8) = *(short8*)&row[8];
}

// ---------------------------------------------------------------------------
// y_cm (bf16 [H][M]) -> y_pm (bf16 [M][H])
__global__ __launch_bounds__(256) void k_y2pm(const __hip_bfloat16* __restrict__ ycm,
    __hip_bfloat16* __restrict__ ypm)
{
    __shared__ __hip_bfloat16 lds[64][68];
    int pos0 = blockIdx.x * 64, ch0 = blockIdx.y * 64;
    int tid = threadIdx.x;
    int ch = tid >> 2, p0 = (tid & 3) * 16;
    const __hip_bfloat16* src = ycm + (size_t)(ch0 + ch) * M_ + pos0 + p0;
    #pragma unroll
    for (int k = 0; k < 4; k++)
        *(short4v*)&lds[ch][p0 + k*4] = *(const short4v*)(src + k*4);
    __syncthreads();
    int pp = tid >> 2, c0 = (tid & 3) * 16;
    alignas(16) __hip_bfloat16 row[16];
    #pragma unroll
    for (int k = 0; k < 16; k++) row[k] = lds[c0 + k][pp];
    size_t base = (size_t)(pos0 + pp) * H_ + ch0 + c0;
    *(short8*)(ypm + base)     = *(short8*)&row[0];
    *(short8*)(ypm + base + 8) = *(short8*)&row[8];
}

// ---------------------------------------------------------------------------
// chunk local final states: per channel, S[g][m] = sum_j Wtr[m][j] u[g*64+j]
__global__ __launch_bounds__(256) void k_state(const __hip_bfloat16* __restrict__ ucm,
    const __hip_bfloat16* __restrict__ mw, __hip_bfloat16* __restrict__ st)
{
    int h = blockIdx.x >> 3, slab = blockIdx.x & 7;
    int g0 = slab * 64;
    int tid = threadIdx.x, w = tid >> 6, l = tid & 63, l15 = l & 15, l4 = l >> 4;
    const __hip_bfloat16* abase = ucm + (size_t)h * M_ + (size_t)(g0 + w*16 + l15) * 64 + l4*8;
    const __hip_bfloat16* bbase = mw + (size_t)h * 4096 + l15*64 + l4*8;
    f32x4 acc[4];
    #pragma unroll
    for (int nj = 0; nj < 4; nj++) acc[nj] = (f32x4)0.f;
    #pragma unroll
    for (int ks = 0; ks < 2; ks++) {
        bf16x8 a = *(const bf16x8*)(abase + ks*32);
        #pragma unroll
        for (int nj = 0; nj < 4; nj++) {
            bf16x8 b = *(const bf16x8*)(bbase + nj*16*64 + ks*32);
            acc[nj] = __builtin_amdgcn_mfma_f32_16x16x32_bf16(a, b, acc[nj], 0, 0, 0);
        }
    }
    #pragma unroll
    for (int nj = 0; nj < 4; nj++)
        #pragma unroll
        for (int r = 0; r < 4; r++) {
            int g = g0 + w*16 + l4*4 + r;
            st[((size_t)h*GCH + g)*64 + nj*16 + l15] = __float2bfloat16(acc[nj][r]);
        }
}

// ---------------------------------------------------------------------------
// segmented scan over chunks (channel-major st, bf16), carries f32
__global__ __launch_bounds__(256) void k_scan_a(const float* __restrict__ ws, int layer,
    const __hip_bfloat16* __restrict__ st, float* __restrict__ seg)
{
    int gid = blockIdx.x * 256 + threadIdx.x;   // H*B*SEG*N2 = 262144
    int n = gid & 31, s = (gid >> 5) & 7, b = (gid >> 8) & 3, h = gid >> 10;
    float2 wl = ((const float2*)(ws + OFF_PWLC))[(size_t)layer*H_*N2_ + h*32 + n];
    const __hip_bfloat16* base = st + ((size_t)h*GCH + b*128 + s*SEGC) * 64 + 2*n;
    float ar = 0.f, ai = 0.f;
    #pragma unroll
    for (int j = 0; j < SEGC; j++) {
        float2 v = __bfloat1622float2(*(const __hip_bfloat162*)(base + j*64));
        float tr = fmaf(wl.x, ar, v.x); tr = fmaf(-wl.y, ai, tr);
        float ti = fmaf(wl.x, ai, v.y); ti = fmaf(wl.y, ar, ti);
        ar = tr; ai = ti;
    }
    ((float2*)seg)[((size_t)(h*B_ + b)*SEG + s)*32 + n] = make_float2(ar, ai);
}

__global__ __launch_bounds__(256) void k_scan_b(const float* __restrict__ ws, int layer,
    float* __restrict__ seg)
{
    int gid = blockIdx.x * 256 + threadIdx.x;   // H*B*N2 = 32768
    int n = gid & 31, b = (gid >> 5) & 3, h = gid >> 7;
    float2 wl = ((const float2*)(ws + OFF_PWLC))[(size_t)layer*H_*N2_ + h*32 + n];
    float wr = wl.x, wi = wl.y;
    #pragma unroll
    for (int q = 0; q < 4; q++) {               // wl^16
        float nr = wr*wr - wi*wi, ni = 2.f*wr*wi;
        wr = nr; wi = ni;
    }
    float2* sp = (float2*)seg;
    float ar = 0.f, ai = 0.f;
    #pragma unroll
    for (int s = 0; s < SEG; s++) {
        size_t idx = ((size_t)(h*B_ + b)*SEG + s)*32 + n;
        float2 v = sp[idx];
        sp[idx] = make_float2(ar, ai);
        float tr = fmaf(wr, ar, v.x); tr = fmaf(-wi, ai, tr);
        float ti = fmaf(wr, ai, v.y); ti = fmaf(wi, ar, ti);
        ar = tr; ai = ti;
    }
}

__global__ __launch_bounds__(256) void k_scan_c(const float* __restrict__ ws, int layer,
    const float* __restrict__ seg, __hip_bfloat16* __restrict__ st)
{
    int gid = blockIdx.x * 256 + threadIdx.x;
    int n = gid & 31, s = (gid >> 5) & 7, b = (gid >> 8) & 3, h = gid >> 10;
    float2 wl = ((const float2*)(ws + OFF_PWLC))[(size_t)layer*H_*N2_ + h*32 + n];
    float2 c0 = ((const float2*)seg)[((size_t)(h*B_ + b)*SEG + s)*32 + n];
    float ar = c0.x, ai = c0.y;
    __hip_bfloat16* base = st + ((size_t)h*GCH + b*128 + s*SEGC) * 64 + 2*n;
    #pragma unroll
    for (int j = 0; j < SEGC; j++) {
        float2 v = __bfloat1622float2(*(const __hip_bfloat162*)(base + j*64));
        *(__hip_bfloat162*)(base + j*64) = __float22bfloat162_rn(make_float2(ar, ai));
        float tr = fmaf(wl.x, ar, v.x); tr = fmaf(-wl.y, ai, tr);
        float ti = fmaf(wl.x, ai, v.y); ti = fmaf(wl.y, ar, ti);
        ar = tr; ai = ti;
    }
}

// ---------------------------------------------------------------------------
// conv via MFMA: Y[g][t] = sum_j Ttr[t][j] u[g*64+j] + sum_m Vtr[t][m] S[g][m]
// then y = gelu(Y + D*u), written bf16 channel-major.
__global__ __launch_bounds__(256) void k_conv2(const __hip_bfloat16* __restrict__ ucm,
    const __hip_bfloat16* __restrict__ st, const __hip_bfloat16* __restrict__ mt,
    const __hip_bfloat16* __restrict__ mv, const float* __restrict__ Dp, int layer,
    __hip_bfloat16* __restrict__ ycm)
{
    int h = blockIdx.x >> 3, slab = blockIdx.x & 7;
    int g0 = slab * 64;
    int tid = threadIdx.x, w = tid >> 6, l = tid & 63, l15 = l & 15, l4 = l >> 4;
    const __hip_bfloat16* au = ucm + (size_t)h*M_ + (size_t)(g0 + w*16 + l15)*64 + l4*8;
    const __hip_bfloat16* as = st + ((size_t)h*GCH + g0 + w*16 + l15)*64 + l4*8;
    const __hip_bfloat16* bt = mt + (size_t)h*4096 + l15*64 + l4*8;
    const __hip_bfloat16* bv = mv + (size_t)h*4096 + l15*64 + l4*8;
    f32x4 acc[4];
    #pragma unroll
    for (int nj = 0; nj < 4; nj++) acc[nj] = (f32x4)0.f;
    #pragma unroll
    for (int ks = 0; ks < 2; ks++) {
        bf16x8 a = *(const bf16x8*)(au + ks*32);
        #pragma unroll
        for (int nj = 0; nj < 4; nj++) {
            bf16x8 b = *(const bf16x8*)(bt + nj*16*64 + ks*32);
            acc[nj] = __builtin_amdgcn_mfma_f32_16x16x32_bf16(a, b, acc[nj], 0, 0, 0);
        }
    }
    #pragma unroll
    for (int ks = 0; ks < 2; ks++) {
        bf16x8 a = *(const bf16x8*)(as + ks*32);
        #pragma unroll
        for (int nj = 0; nj < 4; nj++) {
            bf16x8 b = *(const bf16x8*)(bv + nj*16*64 + ks*32);
            acc[nj] = __builtin_amdgcn_mfma_f32_16x16x32_bf16(a, b, acc[nj], 0, 0, 0);
        }
    }
    float Dh = Dp[layer * H_ + h];
    #pragma unroll
    for (int nj = 0; nj < 4; nj++)
        #pragma unroll
        for (int r = 0; r < 4; r++) {
            int g = g0 + w*16 + l4*4 + r;
            size_t p = (size_t)h*M_ + (size_t)g*64 + nj*16 + l15;
            float uv = __bfloat162float(ucm[p]);
            float v = fmaf(Dh, uv, acc[nj][r]);
            float gg = 0.7978845608028654f * fmaf(0.044715f * v, v * v, v);
            float yv = v / (1.f + __expf(-2.f * gg));
            ycm[p] = __float2bfloat16(yv);
        }
}

// ---------------------------------------------------------------------------
// fused MFMA: u = y @ Wo^T + bo ; z = u[:256]*sigmoid(u[256:]) ; h = LN(z+h)
__global__ __launch_bounds__(256) void k_glu_mfma(
    const __hip_bfloat16* __restrict__ yb,   // [M,256] bf16
    float* __restrict__ h,                   // [M,256] f32 in/out
    const __hip_bfloat16* __restrict__ wob,  // [512,256] bf16
    const float* __restrict__ bo, const float* __restrict__ lnw,
    const float* __restrict__ lnb)
{
    int tid = threadIdx.x;
    int w   = tid >> 6;
    int l   = tid & 63;
    int l15 = l & 15, l4 = l >> 4;
    int m0  = blockIdx.x * 64;
    int nv  = w * 64;
    f32x4 accv[4][4], accg[4][4];
    #pragma unroll
    for (int mi = 0; mi < 4; mi++)
        #pragma unroll
        for (int nj = 0; nj < 4; nj++) { accv[mi][nj] = (f32x4)0.f; accg[mi][nj] = (f32x4)0.f; }

    #pragma unroll 1
    for (int ks = 0; ks < 8; ks++) {
        int k0 = ks * 32 + l4 * 8;
        bf16x8 a[4];
        #pragma unroll
        for (int mi = 0; mi < 4; mi++)
            a[mi] = *(const bf16x8*)(yb + (size_t)(m0 + mi * 16 + l15) * H_ + k0);
        #pragma unroll
        for (int nj = 0; nj < 4; nj++) {
            bf16x8 bv = *(const bf16x8*)(wob + (size_t)(nv + nj * 16 + l15) * H_ + k0);
            bf16x8 bg = *(const bf16x8*)(wob + (size_t)(256 + nv + nj * 16 + l15) * H_ + k0);
            #pragma unroll
            for (int mi = 0; mi < 4; mi++) {
                accv[mi][nj] = __builtin_amdgcn_mfma_f32_16x16x32_bf16(a[mi], bv, accv[mi][nj], 0, 0, 0);
                accg[mi][nj] = __builtin_amdgcn_mfma_f32_16x16x32_bf16(a[mi], bg, accg[mi][nj], 0, 0, 0);
            }
        }
    }

    float bov[4], bog[4], lw[4], lb[4];
    #pragma unroll
    for (int nj = 0; nj < 4; nj++) {
        int cn = nv + nj * 16 + l15;
        bov[nj] = bo[cn]; bog[nj] = bo[256 + cn];
        lw[nj] = lnw[cn]; lb[nj] = lnb[cn];
    }
    __shared__ float red[4][64][2];
    #pragma unroll
    for (int mi = 0; mi < 4; mi++) {
        #pragma unroll
        for (int r = 0; r < 4; r++) {
            int lr = mi * 16 + l4 * 4 + r;
            size_t row = (size_t)(m0 + lr);
            float s = 0.f, ss = 0.f;
            #pragma unroll
            for (int nj = 0; nj < 4; nj++) {
                float uv = accv[mi][nj][r] + bov[nj];
                float ug = accg[mi][nj][r] + bog[nj];
                float z = uv / (1.f + __expf(-ug));
                float v = z + h[row * H_ + nv + nj * 16 + l15];
                accv[mi][nj][r] = v;
                s += v; ss += v * v;
            }
            #pragma unroll
            for (int off = 1; off < 16; off <<= 1) {
                s  += __shfl_xor(s, off);
                ss += __shfl_xor(ss, off);
            }
            if (l15 == 0) { red[w][lr][0] = s; red[w][lr][1] = ss; }
        }
    }
    __syncthreads();
    #pragma unroll
    for (int mi = 0; mi < 4; mi++) {
        #pragma unroll
        for (int r = 0; r < 4; r++) {
            int lr = mi * 16 + l4 * 4 + r;
            size_t row = (size_t)(m0 + lr);
            float s  = red[0][lr][0] + red[1][lr][0] + red[2][lr][0] + red[3][lr][0];
            float ss = red[0][lr][1] + red[1][lr][1] + red[2][lr][1] + red[3][lr][1];
            float mu = s * (1.f / 256.f);
            float var = ss * (1.f / 256.f) - mu * mu;
            float rstd = rsqrtf(var + 1e-5f);
            #pragma unroll
            for (int nj = 0; nj < 4; nj++)
                h[row * H_ + nv + nj * 16 + l15] =
                    (accv[mi][nj][r] - mu) * rstd * lw[nj] + lb[nj];
        }
    }
}

// ---------------------------------------------------------------------------
__global__ __launch_bounds__(256) void k_decoder(const float* __restrict__ h,
    const float* __restrict__ out_W, const float* __restrict__ out_b,
    float* __restrict__ out)
{
    __shared__ float hs[16][260];
    __shared__ float wl[10][260];
    int p0 = blockIdx.x * 16;
    int tid = threadIdx.x;
    const float4* h4 = (const float4*)h;
    #pragma unroll
    for (int it = 0; it < 4; it++) {
        int q = it * 256 + tid;
        int r = q >> 6, k4 = q & 63;
        float4 v = h4[(size_t)(p0 + r) * 64 + k4];
        *(float4*)&hs[r][k4 * 4] = v;
    }
    for (int q = tid; q < 640; q += 256) {
        int r = q / 64, k4 = q % 64;
        *(float4*)&wl[r][k4 * 4] = ((const float4*)out_W)[q];
    }
    __syncthreads();
    int slot = tid & 15, pl = tid >> 4;
    if (slot < DOUT) {
        float a0 = 0.f, a1 = 0.f, a2 = 0.f, a3 = 0.f;
        #pragma unroll 8
        for (int k = 0; k < 256; k += 4) {
            a0 = fmaf(hs[pl][k + 0], wl[slot][k + 0], a0);
            a1 = fmaf(hs[pl][k + 1], wl[slot][k + 1], a1);
            a2 = fmaf(hs[pl][k + 2], wl[slot][k + 2], a2);
            a3 = fmaf(hs[pl][k + 3], wl[slot][k + 3], a3);
        }
        out[(size_t)(p0 + pl) * DOUT + slot] = (a0 + a1) + (a2 + a3) + out_b[slot];
    }
}

// ---------------------------------------------------------------------------
extern "C" void kernel_launch(void* const* d_in, const int* in_sizes, int n_in,
                              void* d_out, int out_size, void* d_ws, size_t ws_size,
                              hipStream_t stream)
{
    (void)in_sizes; (void)n_in; (void)out_size; (void)ws_size;
    const float* x        = (const float*)d_in[0];
    const float* enc_W    = (const float*)d_in[1];
    const float* enc_b    = (const float*)d_in[2];
    const float* log_dt   = (const float*)d_in[3];
    const float* log_A_re = (const float*)d_in[4];
    const float* A_im     = (const float*)d_in[5];
    const float* C_re     = (const float*)d_in[6];
    const float* C_im     = (const float*)d_in[7];
    const float* Dp       = (const float*)d_in[8];
    const float* Wo       = (const float*)d_in[9];
    const float* bo       = (const float*)d_in[10];
    const float* lnw      = (const float*)d_in[11];
    const float* lnb      = (const float*)d_in[12];
    const float* out_W    = (const float*)d_in[13];
    const float* out_b    = (const float*)d_in[14];
    float* ws = (float*)d_ws;
    float* h  = ws + OFF_H;
    __hip_bfloat16* ucm = (__hip_bfloat16*)(ws + OFF_UCM);   // also y_pm alias
    __hip_bfloat16* ycm = (__hip_bfloat16*)(ws + OFF_YCM);
    __hip_bfloat16* stb = (__hip_bfloat16*)(ws + OFF_ST);
    float* segf = ws + OFF_SEG;
    __hip_bfloat16* mt = (__hip_bfloat16*)(ws + OFF_MT);
    __hip_bfloat16* mw = (__hip_bfloat16*)(ws + OFF_MW);
    __hip_bfloat16* mv = (__hip_bfloat16*)(ws + OFF_MV);
    __hip_bfloat16* wob = (__hip_bfloat16*)(ws + OFF_WOB);

    k_params<<<NL_ * H_ * N2_ / 256, 256, 0, stream>>>(log_dt, log_A_re, A_im, C_re, C_im, ws);
    dim3 tb(32, 8);
    k_transpose<<<dim3(DIN / 32, H_ / 32), tb, 0, stream>>>(enc_W, ws + OFF_EWT, H_, DIN);
    k_wcvt<<<(NL_ * 2 * H_ * H_ / 4 + 255) / 256, 256, 0, stream>>>(Wo, wob, NL_ * 2 * H_ * H_ / 4);
    k_encoder<<<M_ / 32, 256, 0, stream>>>(x, ws + OFF_EWT, enc_b, h);
    for (int i = 0; i < NL_; i++) {
        k_mats<<<H_, 256, 0, stream>>>(ws, i, mt, mw, mv);
        k_h2cm<<<dim3(M_ / 64, H_ / 64), 256, 0, stream>>>(h, ucm);
        k_state<<<H_ * 8, 256, 0, stream>>>(ucm, mw, stb);
        k_scan_a<<<H_ * B_ * SEG * N2_ / 256, 256, 0, stream>>>(ws, i, stb, segf);
        k_scan_b<<<H_ * B_ * N2_ / 256, 256, 0, stream>>>(ws, i, segf);
        k_scan_c<<<H_ * B_ * SEG * N2_ / 256, 256, 0, stream>>>(ws, i, segf, stb);
        k_conv2<<<H_ * 8, 256, 0, stream>>>(ucm, stb, mt, mv, Dp, i, ycm);
        k_y2pm<<<dim3(M_ / 64, H_ / 64), 256, 0, stream>>>(ycm, ucm);
        k_glu_mfma<<<M_ / 64, 256, 0, stream>>>(ucm, h,
            wob + (size_t)i * 2 * H_ * H_, bo + (size_t)i * 2 * H_,
            lnw + (size_t)i * H_, lnb + (size_t)i * H_);
    }
    k_decoder<<<M_ / 16, 256, 0, stream>>>(h, out_W, out_b, (float*)d_out);
}

// Round 5
// 544.669 us; speedup vs baseline: 1.4933x; 1.0238x over previous
//
#include <hip/hip_runtime.h>
#include <hip/hip_bf16.h>

// ---------------------------------------------------------------------------
// S4D stack, MFMA everywhere:
// encoder GEMM(+cm write) -> 4x[ mats; chunk-state MFMA; fused LDS scan;
//   Toeplitz conv MFMA; cm->pm transpose; GLU MFMA + LN (+cm write) ] -> dec.
// h fp32 position-major; u/y/st bf16 channel-major; ws ~92 MB.
// ---------------------------------------------------------------------------

constexpr int B_ = 4, L_ = 8192, DIN = 64, H_ = 256, N2_ = 32, NL_ = 4, DOUT = 10;
constexpr int LC = 64, CHK = L_ / LC;     // 128 chunks/batch
constexpr int GCH = B_ * CHK;             // 512 global chunks
constexpr int M_ = B_ * L_;               // 32768 positions

// ws layout in float slots
constexpr size_t OFF_H    = 0;                         // f32 [M][H]
constexpr size_t OFF_WOB  = 8388608;                   // bf16 Wo NL*512*256
constexpr size_t OFF_PW   = 8650752;                   // (unused legacy)
constexpr size_t OFF_PCT  = 8716288;                   // f32 Ct2 pairs
constexpr size_t OFF_PWLC = 8781824;                   // f32 w^64 pairs
constexpr size_t OFF_PZ   = 8847360;                   // f32 z=dtA pairs
constexpr size_t OFF_EWT  = 8912896;                   // f32 enc W^T
constexpr size_t OFF_UCM  = 8929280;                   // bf16 [H][M] u cm
constexpr size_t OFF_YCM  = 13123584;                  // bf16 [H][M] y cm
constexpr size_t OFF_ST   = 17317888;                  // bf16 [H][GCH][64]; aliased y_pm
constexpr size_t OFF_MT   = 21512192;                  // bf16 Ttr [H][64][64]
constexpr size_t OFF_MW   = 22036480;                  // bf16 Wtr
constexpr size_t OFF_MV   = 22560768;                  // bf16 Vtr
// end 23085056 slots = 92.3 MB

typedef short bf16x8 __attribute__((ext_vector_type(8)));
typedef short short8 __attribute__((ext_vector_type(8)));
typedef float f32x4  __attribute__((ext_vector_type(4)));

// ---------------------------------------------------------------------------
__global__ __launch_bounds__(256) void k_params(
    const float* __restrict__ log_dt, const float* __restrict__ log_A_re,
    const float* __restrict__ A_im, const float* __restrict__ C_re,
    const float* __restrict__ C_im, float* __restrict__ ws)
{
    int idx = blockIdx.x * 256 + threadIdx.x;     // over NL*H*N2
    if (idx >= NL_ * H_ * N2_) return;
    int i  = idx / (H_ * N2_);
    int hh = (idx / N2_) % H_;
    float dt  = expf(log_dt[i * H_ + hh]);
    float Are = -expf(log_A_re[idx]);
    float Aim = A_im[idx];
    float zre = dt * Are, zim = dt * Aim;
    float er  = expf(zre);
    float wre = er * cosf(zim), wim = er * sinf(zim);
    float d   = Are * Are + Aim * Aim;
    float nre = wre - 1.f, nim = wim;
    float qre = (nre * Are + nim * Aim) / d;
    float qim = (nim * Are - nre * Aim) / d;
    float cr = C_re[idx], ci = C_im[idx];
    float ctre = cr * qre - ci * qim;
    float ctim = cr * qim + ci * qre;
    float er2 = expf(zre * (float)LC);
    float wlre = er2 * cosf(zim * (float)LC);
    float wlim = er2 * sinf(zim * (float)LC);
    ((float2*)(ws + OFF_PW))[idx]   = make_float2(wre, wim);
    ((float2*)(ws + OFF_PCT))[idx]  = make_float2(2.f * ctre, 2.f * ctim);
    ((float2*)(ws + OFF_PWLC))[idx] = make_float2(wlre, wlim);
    ((float2*)(ws + OFF_PZ))[idx]   = make_float2(zre, zim);
}

// ---------------------------------------------------------------------------
// per-channel bf16 matrices: Ttr[t][j]=k[t-j], Wtr[m][j], Vtr[t][m]
__global__ __launch_bounds__(256) void k_mats(const float* __restrict__ ws,
    int layer, __hip_bfloat16* __restrict__ mt, __hip_bfloat16* __restrict__ mw,
    __hip_bfloat16* __restrict__ mv)
{
    int h = blockIdx.x, tid = threadIdx.x;
    __shared__ float zre[32], zim[32], ctr[32], cti[32], kv[64];
    if (tid < 32) {
        float2 z = ((const float2*)(ws + OFF_PZ))[(size_t)layer*H_*N2_ + h*N2_ + tid];
        float2 c = ((const float2*)(ws + OFF_PCT))[(size_t)layer*H_*N2_ + h*N2_ + tid];
        zre[tid] = z.x; zim[tid] = z.y; ctr[tid] = c.x; cti[tid] = c.y;
    }
    __syncthreads();
    if (tid < 64) {
        float d = (float)tid, acc = 0.f;
        for (int n = 0; n < 32; n++) {
            float er = expf(zre[n] * d);
            float co = cosf(zim[n] * d), si = sinf(zim[n] * d);
            acc += er * (ctr[n] * co - cti[n] * si);
        }
        kv[tid] = acc;
    }
    __syncthreads();
    {   // Ttr
        int t = tid >> 2, j0 = (tid & 3) * 16;
        alignas(16) __hip_bfloat16 row[16];
        #pragma unroll
        for (int jj = 0; jj < 16; jj++) {
            int j = j0 + jj;
            row[jj] = __float2bfloat16(j <= t ? kv[t - j] : 0.f);
        }
        *(short8*)(mt + (size_t)h*4096 + t*64 + j0)     = *(short8*)&row[0];
        *(short8*)(mt + (size_t)h*4096 + t*64 + j0 + 8) = *(short8*)&row[8];
    }
    {   // Wtr
        int n = tid >> 3, j0 = (tid & 7) * 8;
        alignas(16) __hip_bfloat16 rre[8], rim[8];
        #pragma unroll
        for (int jj = 0; jj < 8; jj++) {
            float e = (float)(63 - (j0 + jj));
            float er = expf(zre[n] * e);
            rre[jj] = __float2bfloat16(er * cosf(zim[n] * e));
            rim[jj] = __float2bfloat16(er * sinf(zim[n] * e));
        }
        *(short8*)(mw + (size_t)h*4096 + (2*n)*64 + j0)   = *(short8*)&rre[0];
        *(short8*)(mw + (size_t)h*4096 + (2*n+1)*64 + j0) = *(short8*)&rim[0];
    }
    {   // Vtr
        int t = tid >> 2, n0 = (tid & 3) * 8;
        float e = (float)(t + 1);
        alignas(16) __hip_bfloat16 row[16];
        #pragma unroll
        for (int k = 0; k < 8; k++) {
            int n = n0 + k;
            float er = expf(zre[n] * e);
            float wr = er * cosf(zim[n] * e), wi = er * sinf(zim[n] * e);
            row[2*k]   = __float2bfloat16(ctr[n]*wr - cti[n]*wi);
            row[2*k+1] = __float2bfloat16(-(ctr[n]*wi + cti[n]*wr));
        }
        *(short8*)(mv + (size_t)h*4096 + t*64 + 2*n0)     = *(short8*)&row[0];
        *(short8*)(mv + (size_t)h*4096 + t*64 + 2*n0 + 8) = *(short8*)&row[8];
    }
}

// ---------------------------------------------------------------------------
__global__ __launch_bounds__(256) void k_transpose(const float* __restrict__ src,
    float* __restrict__ dst, int R, int Cc)
{
    __shared__ float t[32][33];
    int x = blockIdx.x * 32 + threadIdx.x;
    #pragma unroll
    for (int i = 0; i < 4; i++) {
        int yy = blockIdx.y * 32 + threadIdx.y + i * 8;
        if (x < Cc && yy < R) t[threadIdx.y + i * 8][threadIdx.x] = src[(size_t)yy * Cc + x];
    }
    __syncthreads();
    int xo = blockIdx.y * 32 + threadIdx.x;
    #pragma unroll
    for (int i = 0; i < 4; i++) {
        int yo = blockIdx.x * 32 + threadIdx.y + i * 8;
        if (xo < R && yo < Cc) dst[(size_t)yo * R + xo] = t[threadIdx.x][threadIdx.y + i * 8];
    }
}

// ---------------------------------------------------------------------------
__global__ __launch_bounds__(256) void k_wcvt(const float* __restrict__ src,
    __hip_bfloat16* __restrict__ dst, int n4)
{
    int i = blockIdx.x * 256 + threadIdx.x;
    if (i >= n4) return;
    float4 v = ((const float4*)src)[i];
    union { __hip_bfloat16 b[4]; uint2 u; } o;
    o.b[0] = __float2bfloat16(v.x); o.b[1] = __float2bfloat16(v.y);
    o.b[2] = __float2bfloat16(v.z); o.b[3] = __float2bfloat16(v.w);
    ((uint2*)dst)[i] = o.u;
}

// ---------------------------------------------------------------------------
// encoder: h[M,256] = x @ encWT + b; also writes ucm bf16 channel-major
__global__ __launch_bounds__(256) void k_encoder(const float* __restrict__ x,
    const float* __restrict__ encWT, const float* __restrict__ enc_b,
    float* __restrict__ h, __hip_bfloat16* __restrict__ ucm)
{
    __shared__ float As[DIN][36];
    __shared__ float Bs[32][256];
    int m0 = blockIdx.x * 32;
    int tid = threadIdx.x;
    const float4* x4 = (const float4*)x;
    #pragma unroll
    for (int q = 0; q < 2; q++) {
        int f = tid * 2 + q;
        int row = f >> 4, kq = f & 15;
        float4 v = x4[(size_t)(m0 + row) * 16 + kq];
        As[kq * 4 + 0][row] = v.x; As[kq * 4 + 1][row] = v.y;
        As[kq * 4 + 2][row] = v.z; As[kq * 4 + 3][row] = v.w;
    }
    int tx = tid & 31, ty = tid >> 5;
    float acc[4][8];
    #pragma unroll
    for (int p = 0; p < 4; p++)
        #pragma unroll
        for (int j = 0; j < 8; j++) acc[p][j] = 0.f;
    const float4* w4 = (const float4*)encWT;
    for (int ks = 0; ks < 2; ks++) {
        __syncthreads();
        #pragma unroll
        for (int it = 0; it < 8; it++) {
            int q = it * 256 + tid;
            ((float4*)Bs)[q] = w4[ks * 2048 + q];
        }
        __syncthreads();
        #pragma unroll 8
        for (int kk = 0; kk < 32; kk++) {
            int k = ks * 32 + kk;
            float4 a  = *(const float4*)&As[k][ty * 4];
            float4 b0 = *(const float4*)&Bs[kk][tx * 4];
            float4 b1 = *(const float4*)&Bs[kk][128 + tx * 4];
            float av[4] = {a.x, a.y, a.z, a.w};
            float bv[8] = {b0.x, b0.y, b0.z, b0.w, b1.x, b1.y, b1.z, b1.w};
            #pragma unroll
            for (int p = 0; p < 4; p++)
                #pragma unroll
                for (int j = 0; j < 8; j++)
                    acc[p][j] = fmaf(av[p], bv[j], acc[p][j]);
        }
    }
    float4 eb0 = *(const float4*)&enc_b[tx * 4];
    float4 eb1 = *(const float4*)&enc_b[128 + tx * 4];
    float ebv[8] = {eb0.x, eb0.y, eb0.z, eb0.w, eb1.x, eb1.y, eb1.z, eb1.w};
    __syncthreads();                         // Bs dead -> reuse as lt
    __hip_bfloat16* lt = (__hip_bfloat16*)&Bs[0][0];   // [256][40] bf16
    float4* h4 = (float4*)h;
    #pragma unroll
    for (int p = 0; p < 4; p++) {
        size_t pos = m0 + ty * 4 + p;
        int pl = ty * 4 + p;
        float ov[8];
        #pragma unroll
        for (int j = 0; j < 8; j++) ov[j] = acc[p][j] + ebv[j];
        h4[pos * 64 + tx]      = make_float4(ov[0], ov[1], ov[2], ov[3]);
        h4[pos * 64 + 32 + tx] = make_float4(ov[4], ov[5], ov[6], ov[7]);
        #pragma unroll
        for (int jj = 0; jj < 4; jj++) {
            lt[(tx * 4 + jj) * 40 + pl]       = __float2bfloat16(ov[jj]);
            lt[(128 + tx * 4 + jj) * 40 + pl] = __float2bfloat16(ov[jj + 4]);
        }
    }
    __syncthreads();
    #pragma unroll
    for (int q = 0; q < 4; q++)
        *(short8*)(ucm + (size_t)tid * M_ + m0 + q * 8) = *(short8*)&lt[tid * 40 + q * 8];
}

// ---------------------------------------------------------------------------
// chunk local final states: per channel, S[g][m] = sum_j Wtr[m][j] u[g*64+j]
__global__ __launch_bounds__(256) void k_state(const __hip_bfloat16* __restrict__ ucm,
    const __hip_bfloat16* __restrict__ mw, __hip_bfloat16* __restrict__ st)
{
    int h = blockIdx.x >> 3, slab = blockIdx.x & 7;
    int g0 = slab * 64;
    int tid = threadIdx.x, w = tid >> 6, l = tid & 63, l15 = l & 15, l4 = l >> 4;
    const __hip_bfloat16* abase = ucm + (size_t)h * M_ + (size_t)(g0 + w*16 + l15) * 64 + l4*8;
    const __hip_bfloat16* bbase = mw + (size_t)h * 4096 + l15*64 + l4*8;
    f32x4 acc[4];
    #pragma unroll
    for (int nj = 0; nj < 4; nj++) acc[nj] = (f32x4)0.f;
    #pragma unroll
    for (int ks = 0; ks < 2; ks++) {
        bf16x8 a = *(const bf16x8*)(abase + ks*32);
        #pragma unroll
        for (int nj = 0; nj < 4; nj++) {
            bf16x8 b = *(const bf16x8*)(bbase + nj*16*64 + ks*32);
            acc[nj] = __builtin_amdgcn_mfma_f32_16x16x32_bf16(a, b, acc[nj], 0, 0, 0);
        }
    }
    #pragma unroll
    for (int nj = 0; nj < 4; nj++)
        #pragma unroll
        for (int r = 0; r < 4; r++) {
            int g = g0 + w*16 + l4*4 + r;
            st[((size_t)h*GCH + g)*64 + nj*16 + l15] = __float2bfloat16(acc[nj][r]);
        }
}

// ---------------------------------------------------------------------------
// fused scan: block = channel; stage st[h] (64KB) to LDS, serial scan per (b,n)
__global__ __launch_bounds__(256) void k_scan(const float* __restrict__ ws, int layer,
    __hip_bfloat16* __restrict__ st)
{
    __shared__ __hip_bfloat16 s[GCH * 64];   // 64 KB
    int h = blockIdx.x, tid = threadIdx.x;
    short8* sp = (short8*)s;
    short8* gp = (short8*)(st + (size_t)h * GCH * 64);
    #pragma unroll
    for (int it = 0; it < 16; it++) sp[it * 256 + tid] = gp[it * 256 + tid];
    __syncthreads();
    if (tid < 128) {
        int b = tid >> 5, n = tid & 31;
        float2 wl = ((const float2*)(ws + OFF_PWLC))[(size_t)layer * H_ * N2_ + h * 32 + n];
        float ar = 0.f, ai = 0.f;
        __hip_bfloat162* base = (__hip_bfloat162*)(s + (size_t)b * 128 * 64) + n;
        for (int c = 0; c < CHK; c++) {
            float2 v = __bfloat1622float2(base[c * 32]);
            base[c * 32] = __float22bfloat162_rn(make_float2(ar, ai));
            float tr = fmaf(wl.x, ar, v.x); tr = fmaf(-wl.y, ai, tr);
            float ti = fmaf(wl.x, ai, v.y); ti = fmaf(wl.y, ar, ti);
            ar = tr; ai = ti;
        }
    }
    __syncthreads();
    #pragma unroll
    for (int it = 0; it < 16; it++) gp[it * 256 + tid] = sp[it * 256 + tid];
}

// ---------------------------------------------------------------------------
// conv via MFMA + carry term, y = gelu(conv + D*u) channel-major
__global__ __launch_bounds__(256) void k_conv2(const __hip_bfloat16* __restrict__ ucm,
    const __hip_bfloat16* __restrict__ st, const __hip_bfloat16* __restrict__ mt,
    const __hip_bfloat16* __restrict__ mv, const float* __restrict__ Dp, int layer,
    __hip_bfloat16* __restrict__ ycm)
{
    int h = blockIdx.x >> 3, slab = blockIdx.x & 7;
    int g0 = slab * 64;
    int tid = threadIdx.x, w = tid >> 6, l = tid & 63, l15 = l & 15, l4 = l >> 4;
    const __hip_bfloat16* au = ucm + (size_t)h*M_ + (size_t)(g0 + w*16 + l15)*64 + l4*8;
    const __hip_bfloat16* as = st + ((size_t)h*GCH + g0 + w*16 + l15)*64 + l4*8;
    const __hip_bfloat16* bt = mt + (size_t)h*4096 + l15*64 + l4*8;
    const __hip_bfloat16* bv = mv + (size_t)h*4096 + l15*64 + l4*8;
    f32x4 acc[4];
    #pragma unroll
    for (int nj = 0; nj < 4; nj++) acc[nj] = (f32x4)0.f;
    #pragma unroll
    for (int ks = 0; ks < 2; ks++) {
        bf16x8 a = *(const bf16x8*)(au + ks*32);
        #pragma unroll
        for (int nj = 0; nj < 4; nj++) {
            bf16x8 b = *(const bf16x8*)(bt + nj*16*64 + ks*32);
            acc[nj] = __builtin_amdgcn_mfma_f32_16x16x32_bf16(a, b, acc[nj], 0, 0, 0);
        }
    }
    #pragma unroll
    for (int ks = 0; ks < 2; ks++) {
        bf16x8 a = *(const bf16x8*)(as + ks*32);
        #pragma unroll
        for (int nj = 0; nj < 4; nj++) {
            bf16x8 b = *(const bf16x8*)(bv + nj*16*64 + ks*32);
            acc[nj] = __builtin_amdgcn_mfma_f32_16x16x32_bf16(a, b, acc[nj], 0, 0, 0);
        }
    }
    float Dh = Dp[layer * H_ + h];
    #pragma unroll
    for (int nj = 0; nj < 4; nj++)
        #pragma unroll
        for (int r = 0; r < 4; r++) {
            int g = g0 + w*16 + l4*4 + r;
            size_t p = (size_t)h*M_ + (size_t)g*64 + nj*16 + l15;
            float uv = __bfloat162float(ucm[p]);
            float v = fmaf(Dh, uv, acc[nj][r]);
            float gg = 0.7978845608028654f * fmaf(0.044715f * v, v * v, v);
            float yv = v / (1.f + __expf(-2.f * gg));
            ycm[p] = __float2bfloat16(yv);
        }
}

// ---------------------------------------------------------------------------
// y_cm -> y_pm transpose
__global__ __launch_bounds__(256) void k_y2pm(const __hip_bfloat16* __restrict__ ycm,
    __hip_bfloat16* __restrict__ ypm)
{
    __shared__ __hip_bfloat16 lds[64][68];
    int pos0 = blockIdx.x * 64, ch0 = blockIdx.y * 64;
    int tid = threadIdx.x;
    int ch = tid >> 2, p0 = (tid & 3) * 16;
    const __hip_bfloat16* src = ycm + (size_t)(ch0 + ch) * M_ + pos0 + p0;
    #pragma unroll
    for (int k = 0; k < 2; k++)
        *(short8*)&lds[ch][p0 + k*8] = *(const short8*)(src + k*8);
    __syncthreads();
    int pp = tid >> 2, c0 = (tid & 3) * 16;
    alignas(16) __hip_bfloat16 row[16];
    #pragma unroll
    for (int k = 0; k < 16; k++) row[k] = lds[c0 + k][pp];
    size_t base = (size_t)(pos0 + pp) * H_ + ch0 + c0;
    *(short8*)(ypm + base)     = *(short8*)&row[0];
    *(short8*)(ypm + base + 8) = *(short8*)&row[8];
}

// ---------------------------------------------------------------------------
// fused MFMA GLU+LN: BM=32, grid M/32=1024; also writes next-layer ucm
__global__ __launch_bounds__(256) void k_glu_mfma(
    const __hip_bfloat16* __restrict__ yb,   // [M,256] bf16 pm
    float* __restrict__ h,                   // [M,256] f32 in/out
    const __hip_bfloat16* __restrict__ wob,  // [512,256] bf16
    const float* __restrict__ bo, const float* __restrict__ lnw,
    const float* __restrict__ lnb, __hip_bfloat16* __restrict__ un)
{
    int tid = threadIdx.x;
    int w = tid >> 6, l = tid & 63, l15 = l & 15, l4 = l >> 4;
    int m0 = blockIdx.x * 32;
    int nv = w * 64;
    f32x4 accv[2][4], accg[2][4];
    #pragma unroll
    for (int mi = 0; mi < 2; mi++)
        #pragma unroll
        for (int nj = 0; nj < 4; nj++) { accv[mi][nj] = (f32x4)0.f; accg[mi][nj] = (f32x4)0.f; }

    #pragma unroll 2
    for (int ks = 0; ks < 8; ks++) {
        int k0 = ks * 32 + l4 * 8;
        bf16x8 a0 = *(const bf16x8*)(yb + (size_t)(m0 + l15) * H_ + k0);
        bf16x8 a1 = *(const bf16x8*)(yb + (size_t)(m0 + 16 + l15) * H_ + k0);
        #pragma unroll
        for (int nj = 0; nj < 4; nj++) {
            bf16x8 bv = *(const bf16x8*)(wob + (size_t)(nv + nj * 16 + l15) * H_ + k0);
            bf16x8 bg = *(const bf16x8*)(wob + (size_t)(256 + nv + nj * 16 + l15) * H_ + k0);
            accv[0][nj] = __builtin_amdgcn_mfma_f32_16x16x32_bf16(a0, bv, accv[0][nj], 0, 0, 0);
            accg[0][nj] = __builtin_amdgcn_mfma_f32_16x16x32_bf16(a0, bg, accg[0][nj], 0, 0, 0);
            accv[1][nj] = __builtin_amdgcn_mfma_f32_16x16x32_bf16(a1, bv, accv[1][nj], 0, 0, 0);
            accg[1][nj] = __builtin_amdgcn_mfma_f32_16x16x32_bf16(a1, bg, accg[1][nj], 0, 0, 0);
        }
    }

    float bov[4], bog[4], lw[4], lb[4];
    #pragma unroll
    for (int nj = 0; nj < 4; nj++) {
        int cn = nv + nj * 16 + l15;
        bov[nj] = bo[cn]; bog[nj] = bo[256 + cn];
        lw[nj] = lnw[cn]; lb[nj] = lnb[cn];
    }
    __shared__ float red[4][32][2];
    __shared__ __hip_bfloat16 lt[256 * 40];
    #pragma unroll
    for (int mi = 0; mi < 2; mi++) {
        #pragma unroll
        for (int r = 0; r < 4; r++) {
            int lr = mi * 16 + l4 * 4 + r;
            size_t row = (size_t)(m0 + lr);
            float s = 0.f, ss = 0.f;
            #pragma unroll
            for (int nj = 0; nj < 4; nj++) {
                float uv = accv[mi][nj][r] + bov[nj];
                float ug = accg[mi][nj][r] + bog[nj];
                float z = uv / (1.f + __expf(-ug));
                float v = z + h[row * H_ + nv + nj * 16 + l15];
                accv[mi][nj][r] = v;
                s += v; ss += v * v;
            }
            #pragma unroll
            for (int off = 1; off < 16; off <<= 1) {
                s  += __shfl_xor(s, off);
                ss += __shfl_xor(ss, off);
            }
            if (l15 == 0) { red[w][lr][0] = s; red[w][lr][1] = ss; }
        }
    }
    __syncthreads();
    #pragma unroll
    for (int mi = 0; mi < 2; mi++) {
        #pragma unroll
        for (int r = 0; r < 4; r++) {
            int lr = mi * 16 + l4 * 4 + r;
            size_t row = (size_t)(m0 + lr);
            float s  = red[0][lr][0] + red[1][lr][0] + red[2][lr][0] + red[3][lr][0];
            float ss = red[0][lr][1] + red[1][lr][1] + red[2][lr][1] + red[3][lr][1];
            float mu = s * (1.f / 256.f);
            float var = ss * (1.f / 256.f) - mu * mu;
            float rstd = rsqrtf(var + 1e-5f);
            #pragma unroll
            for (int nj = 0; nj < 4; nj++) {
                int cn = nv + nj * 16 + l15;
                float val = (accv[mi][nj][r] - mu) * rstd * lw[nj] + lb[nj];
                h[row * H_ + cn] = val;
                lt[cn * 40 + lr] = __float2bfloat16(val);
            }
        }
    }
    __syncthreads();
    #pragma unroll
    for (int q = 0; q < 4; q++)
        *(short8*)(un + (size_t)tid * M_ + m0 + q * 8) = *(short8*)&lt[tid * 40 + q * 8];
}

// ---------------------------------------------------------------------------
__global__ __launch_bounds__(256) void k_decoder(const float* __restrict__ h,
    const float* __restrict__ out_W, const float* __restrict__ out_b,
    float* __restrict__ out)
{
    __shared__ float hs[16][260];
    __shared__ float wl[10][260];
    int p0 = blockIdx.x * 16;
    int tid = threadIdx.x;
    const float4* h4 = (const float4*)h;
    #pragma unroll
    for (int it = 0; it < 4; it++) {
        int q = it * 256 + tid;
        int r = q >> 6, k4 = q & 63;
        float4 v = h4[(size_t)(p0 + r) * 64 + k4];
        *(float4*)&hs[r][k4 * 4] = v;
    }
    for (int q = tid; q < 640; q += 256) {
        int r = q / 64, k4 = q % 64;
        *(float4*)&wl[r][k4 * 4] = ((const float4*)out_W)[q];
    }
    __syncthreads();
    int slot = tid & 15, pl = tid >> 4;
    if (slot < DOUT) {
        float a0 = 0.f, a1 = 0.f, a2 = 0.f, a3 = 0.f;
        #pragma unroll 8
        for (int k = 0; k < 256; k += 4) {
            a0 = fmaf(hs[pl][k + 0], wl[slot][k + 0], a0);
            a1 = fmaf(hs[pl][k + 1], wl[slot][k + 1], a1);
            a2 = fmaf(hs[pl][k + 2], wl[slot][k + 2], a2);
            a3 = fmaf(hs[pl][k + 3], wl[slot][k + 3], a3);
        }
        out[(size_t)(p0 + pl) * DOUT + slot] = (a0 + a1) + (a2 + a3) + out_b[slot];
    }
}

// ---------------------------------------------------------------------------
extern "C" void kernel_launch(void* const* d_in, const int* in_sizes, int n_in,
                              void* d_out, int out_size, void* d_ws, size_t ws_size,
                              hipStream_t stream)
{
    (void)in_sizes; (void)n_in; (void)out_size; (void)ws_size;
    const float* x        = (const float*)d_in[0];
    const float* enc_W    = (const float*)d_in[1];
    const float* enc_b    = (const float*)d_in[2];
    const float* log_dt   = (const float*)d_in[3];
    const float* log_A_re = (const float*)d_in[4];
    const float* A_im     = (const float*)d_in[5];
    const float* C_re     = (const float*)d_in[6];
    const float* C_im     = (const float*)d_in[7];
    const float* Dp       = (const float*)d_in[8];
    const float* Wo       = (const float*)d_in[9];
    const float* bo       = (const float*)d_in[10];
    const float* lnw      = (const float*)d_in[11];
    const float* lnb      = (const float*)d_in[12];
    const float* out_W    = (const float*)d_in[13];
    const float* out_b    = (const float*)d_in[14];
    float* ws = (float*)d_ws;
    float* h  = ws + OFF_H;
    __hip_bfloat16* ucm = (__hip_bfloat16*)(ws + OFF_UCM);
    __hip_bfloat16* ycm = (__hip_bfloat16*)(ws + OFF_YCM);
    __hip_bfloat16* stb = (__hip_bfloat16*)(ws + OFF_ST);
    __hip_bfloat16* ypm = (__hip_bfloat16*)(ws + OFF_ST);   // alias: st dead after conv2
    __hip_bfloat16* mt = (__hip_bfloat16*)(ws + OFF_MT);
    __hip_bfloat16* mw = (__hip_bfloat16*)(ws + OFF_MW);
    __hip_bfloat16* mv = (__hip_bfloat16*)(ws + OFF_MV);
    __hip_bfloat16* wob = (__hip_bfloat16*)(ws + OFF_WOB);

    k_params<<<NL_ * H_ * N2_ / 256, 256, 0, stream>>>(log_dt, log_A_re, A_im, C_re, C_im, ws);
    dim3 tb(32, 8);
    k_transpose<<<dim3(DIN / 32, H_ / 32), tb, 0, stream>>>(enc_W, ws + OFF_EWT, H_, DIN);
    k_wcvt<<<(NL_ * 2 * H_ * H_ / 4 + 255) / 256, 256, 0, stream>>>(Wo, wob, NL_ * 2 * H_ * H_ / 4);
    k_encoder<<<M_ / 32, 256, 0, stream>>>(x, ws + OFF_EWT, enc_b, h, ucm);
    for (int i = 0; i < NL_; i++) {
        k_mats<<<H_, 256, 0, stream>>>(ws, i, mt, mw, mv);
        k_state<<<H_ * 8, 256, 0, stream>>>(ucm, mw, stb);
        k_scan<<<H_, 256, 0, stream>>>(ws, i, stb);
        k_conv2<<<H_ * 8, 256, 0, stream>>>(ucm, stb, mt, mv, Dp, i, ycm);
        k_y2pm<<<dim3(M_ / 64, H_ / 64), 256, 0, stream>>>(ycm, ypm);
        k_glu_mfma<<<M_ / 32, 256, 0, stream>>>(ypm, h,
            wob + (size_t)i * 2 * H_ * H_, bo + (size_t)i * 2 * H_,
            lnw + (size_t)i * H_, lnb + (size_t)i * H_, ucm);
    }
    k_decoder<<<M_ / 16, 256, 0, stream>>>(h, out_W, out_b, (float*)d_out);
}

// Round 6
// 509.430 us; speedup vs baseline: 1.5966x; 1.0692x over previous
//
#include <hip/hip_runtime.h>
#include <hip/hip_bf16.h>

// ---------------------------------------------------------------------------
// S4D stack, MFMA everywhere:
// encoder GEMM(+cm write) -> 4x[ mats; fused SSM (state MFMA + LDS scan +
//   Toeplitz conv MFMA); cm->pm transpose; GLU MFMA + LN (+cm write) ] -> dec.
// h fp32 position-major; u/y bf16 channel-major; ws ~92 MB.
// ---------------------------------------------------------------------------

constexpr int B_ = 4, L_ = 8192, DIN = 64, H_ = 256, N2_ = 32, NL_ = 4, DOUT = 10;
constexpr int LC = 64, CHK = L_ / LC;     // 128 chunks/batch
constexpr int GCH = B_ * CHK;             // 512 global chunks
constexpr int M_ = B_ * L_;               // 32768 positions

// ws layout in float slots
constexpr size_t OFF_H    = 0;                         // f32 [M][H]
constexpr size_t OFF_WOB  = 8388608;                   // bf16 Wo NL*512*256
constexpr size_t OFF_PW   = 8650752;                   // (legacy)
constexpr size_t OFF_PCT  = 8716288;                   // f32 Ct2 pairs
constexpr size_t OFF_PWLC = 8781824;                   // f32 w^64 pairs
constexpr size_t OFF_PZ   = 8847360;                   // f32 z=dtA pairs
constexpr size_t OFF_EWT  = 8912896;                   // f32 enc W^T
constexpr size_t OFF_UCM  = 8929280;                   // bf16 [H][M] u cm
constexpr size_t OFF_YCM  = 13123584;                  // bf16 [H][M] y cm
constexpr size_t OFF_ST   = 17317888;                  // bf16 y_pm [M][H]
constexpr size_t OFF_MT   = 21512192;                  // bf16 Ttr [H][64][64]
constexpr size_t OFF_MW   = 22036480;                  // bf16 Wtr
constexpr size_t OFF_MV   = 22560768;                  // bf16 Vtr
// end 23085056 slots = 92.3 MB

typedef short bf16x8 __attribute__((ext_vector_type(8)));
typedef short short8 __attribute__((ext_vector_type(8)));
typedef float f32x4  __attribute__((ext_vector_type(4)));

// ---------------------------------------------------------------------------
__global__ __launch_bounds__(256) void k_params(
    const float* __restrict__ log_dt, const float* __restrict__ log_A_re,
    const float* __restrict__ A_im, const float* __restrict__ C_re,
    const float* __restrict__ C_im, float* __restrict__ ws)
{
    int idx = blockIdx.x * 256 + threadIdx.x;     // over NL*H*N2
    if (idx >= NL_ * H_ * N2_) return;
    int i  = idx / (H_ * N2_);
    int hh = (idx / N2_) % H_;
    float dt  = expf(log_dt[i * H_ + hh]);
    float Are = -expf(log_A_re[idx]);
    float Aim = A_im[idx];
    float zre = dt * Are, zim = dt * Aim;
    float er  = expf(zre);
    float wre = er * cosf(zim), wim = er * sinf(zim);
    float d   = Are * Are + Aim * Aim;
    float nre = wre - 1.f, nim = wim;
    float qre = (nre * Are + nim * Aim) / d;
    float qim = (nim * Are - nre * Aim) / d;
    float cr = C_re[idx], ci = C_im[idx];
    float ctre = cr * qre - ci * qim;
    float ctim = cr * qim + ci * qre;
    float er2 = expf(zre * (float)LC);
    float wlre = er2 * cosf(zim * (float)LC);
    float wlim = er2 * sinf(zim * (float)LC);
    ((float2*)(ws + OFF_PW))[idx]   = make_float2(wre, wim);
    ((float2*)(ws + OFF_PCT))[idx]  = make_float2(2.f * ctre, 2.f * ctim);
    ((float2*)(ws + OFF_PWLC))[idx] = make_float2(wlre, wlim);
    ((float2*)(ws + OFF_PZ))[idx]   = make_float2(zre, zim);
}

// ---------------------------------------------------------------------------
// per-channel bf16 matrices: Ttr[t][j]=k[t-j], Wtr[m][j], Vtr[t][m]
__global__ __launch_bounds__(256) void k_mats(const float* __restrict__ ws,
    int layer, __hip_bfloat16* __restrict__ mt, __hip_bfloat16* __restrict__ mw,
    __hip_bfloat16* __restrict__ mv)
{
    int h = blockIdx.x, tid = threadIdx.x;
    __shared__ float zre[32], zim[32], ctr[32], cti[32], kv[64];
    if (tid < 32) {
        float2 z = ((const float2*)(ws + OFF_PZ))[(size_t)layer*H_*N2_ + h*N2_ + tid];
        float2 c = ((const float2*)(ws + OFF_PCT))[(size_t)layer*H_*N2_ + h*N2_ + tid];
        zre[tid] = z.x; zim[tid] = z.y; ctr[tid] = c.x; cti[tid] = c.y;
    }
    __syncthreads();
    if (tid < 64) {
        float d = (float)tid, acc = 0.f;
        for (int n = 0; n < 32; n++) {
            float er = expf(zre[n] * d);
            float co = cosf(zim[n] * d), si = sinf(zim[n] * d);
            acc += er * (ctr[n] * co - cti[n] * si);
        }
        kv[tid] = acc;
    }
    __syncthreads();
    {   // Ttr
        int t = tid >> 2, j0 = (tid & 3) * 16;
        alignas(16) __hip_bfloat16 row[16];
        #pragma unroll
        for (int jj = 0; jj < 16; jj++) {
            int j = j0 + jj;
            row[jj] = __float2bfloat16(j <= t ? kv[t - j] : 0.f);
        }
        *(short8*)(mt + (size_t)h*4096 + t*64 + j0)     = *(short8*)&row[0];
        *(short8*)(mt + (size_t)h*4096 + t*64 + j0 + 8) = *(short8*)&row[8];
    }
    {   // Wtr
        int n = tid >> 3, j0 = (tid & 7) * 8;
        alignas(16) __hip_bfloat16 rre[8], rim[8];
        #pragma unroll
        for (int jj = 0; jj < 8; jj++) {
            float e = (float)(63 - (j0 + jj));
            float er = expf(zre[n] * e);
            rre[jj] = __float2bfloat16(er * cosf(zim[n] * e));
            rim[jj] = __float2bfloat16(er * sinf(zim[n] * e));
        }
        *(short8*)(mw + (size_t)h*4096 + (2*n)*64 + j0)   = *(short8*)&rre[0];
        *(short8*)(mw + (size_t)h*4096 + (2*n+1)*64 + j0) = *(short8*)&rim[0];
    }
    {   // Vtr
        int t = tid >> 2, n0 = (tid & 3) * 8;
        float e = (float)(t + 1);
        alignas(16) __hip_bfloat16 row[16];
        #pragma unroll
        for (int k = 0; k < 8; k++) {
            int n = n0 + k;
            float er = expf(zre[n] * e);
            float wr = er * cosf(zim[n] * e), wi = er * sinf(zim[n] * e);
            row[2*k]   = __float2bfloat16(ctr[n]*wr - cti[n]*wi);
            row[2*k+1] = __float2bfloat16(-(ctr[n]*wi + cti[n]*wr));
        }
        *(short8*)(mv + (size_t)h*4096 + t*64 + 2*n0)     = *(short8*)&row[0];
        *(short8*)(mv + (size_t)h*4096 + t*64 + 2*n0 + 8) = *(short8*)&row[8];
    }
}

// ---------------------------------------------------------------------------
__global__ __launch_bounds__(256) void k_transpose(const float* __restrict__ src,
    float* __restrict__ dst, int R, int Cc)
{
    __shared__ float t[32][33];
    int x = blockIdx.x * 32 + threadIdx.x;
    #pragma unroll
    for (int i = 0; i < 4; i++) {
        int yy = blockIdx.y * 32 + threadIdx.y + i * 8;
        if (x < Cc && yy < R) t[threadIdx.y + i * 8][threadIdx.x] = src[(size_t)yy * Cc + x];
    }
    __syncthreads();
    int xo = blockIdx.y * 32 + threadIdx.x;
    #pragma unroll
    for (int i = 0; i < 4; i++) {
        int yo = blockIdx.x * 32 + threadIdx.y + i * 8;
        if (xo < R && yo < Cc) dst[(size_t)yo * R + xo] = t[threadIdx.x][threadIdx.y + i * 8];
    }
}

// ---------------------------------------------------------------------------
__global__ __launch_bounds__(256) void k_wcvt(const float* __restrict__ src,
    __hip_bfloat16* __restrict__ dst, int n4)
{
    int i = blockIdx.x * 256 + threadIdx.x;
    if (i >= n4) return;
    float4 v = ((const float4*)src)[i];
    union { __hip_bfloat16 b[4]; uint2 u; } o;
    o.b[0] = __float2bfloat16(v.x); o.b[1] = __float2bfloat16(v.y);
    o.b[2] = __float2bfloat16(v.z); o.b[3] = __float2bfloat16(v.w);
    ((uint2*)dst)[i] = o.u;
}

// ---------------------------------------------------------------------------
// encoder: h[M,256] = x @ encWT + b; also writes ucm bf16 channel-major
__global__ __launch_bounds__(256) void k_encoder(const float* __restrict__ x,
    const float* __restrict__ encWT, const float* __restrict__ enc_b,
    float* __restrict__ h, __hip_bfloat16* __restrict__ ucm)
{
    __shared__ float As[DIN][36];
    __shared__ float Bs[32][256];
    int m0 = blockIdx.x * 32;
    int tid = threadIdx.x;
    const float4* x4 = (const float4*)x;
    #pragma unroll
    for (int q = 0; q < 2; q++) {
        int f = tid * 2 + q;
        int row = f >> 4, kq = f & 15;
        float4 v = x4[(size_t)(m0 + row) * 16 + kq];
        As[kq * 4 + 0][row] = v.x; As[kq * 4 + 1][row] = v.y;
        As[kq * 4 + 2][row] = v.z; As[kq * 4 + 3][row] = v.w;
    }
    int tx = tid & 31, ty = tid >> 5;
    float acc[4][8];
    #pragma unroll
    for (int p = 0; p < 4; p++)
        #pragma unroll
        for (int j = 0; j < 8; j++) acc[p][j] = 0.f;
    const float4* w4 = (const float4*)encWT;
    for (int ks = 0; ks < 2; ks++) {
        __syncthreads();
        #pragma unroll
        for (int it = 0; it < 8; it++) {
            int q = it * 256 + tid;
            ((float4*)Bs)[q] = w4[ks * 2048 + q];
        }
        __syncthreads();
        #pragma unroll 8
        for (int kk = 0; kk < 32; kk++) {
            int k = ks * 32 + kk;
            float4 a  = *(const float4*)&As[k][ty * 4];
            float4 b0 = *(const float4*)&Bs[kk][tx * 4];
            float4 b1 = *(const float4*)&Bs[kk][128 + tx * 4];
            float av[4] = {a.x, a.y, a.z, a.w};
            float bv[8] = {b0.x, b0.y, b0.z, b0.w, b1.x, b1.y, b1.z, b1.w};
            #pragma unroll
            for (int p = 0; p < 4; p++)
                #pragma unroll
                for (int j = 0; j < 8; j++)
                    acc[p][j] = fmaf(av[p], bv[j], acc[p][j]);
        }
    }
    float4 eb0 = *(const float4*)&enc_b[tx * 4];
    float4 eb1 = *(const float4*)&enc_b[128 + tx * 4];
    float ebv[8] = {eb0.x, eb0.y, eb0.z, eb0.w, eb1.x, eb1.y, eb1.z, eb1.w};
    __syncthreads();                         // Bs dead -> reuse as lt
    __hip_bfloat16* lt = (__hip_bfloat16*)&Bs[0][0];   // [256][40] bf16
    float4* h4 = (float4*)h;
    #pragma unroll
    for (int p = 0; p < 4; p++) {
        size_t pos = m0 + ty * 4 + p;
        int pl = ty * 4 + p;
        float ov[8];
        #pragma unroll
        for (int j = 0; j < 8; j++) ov[j] = acc[p][j] + ebv[j];
        h4[pos * 64 + tx]      = make_float4(ov[0], ov[1], ov[2], ov[3]);
        h4[pos * 64 + 32 + tx] = make_float4(ov[4], ov[5], ov[6], ov[7]);
        #pragma unroll
        for (int jj = 0; jj < 4; jj++) {
            lt[(tx * 4 + jj) * 40 + pl]       = __float2bfloat16(ov[jj]);
            lt[(128 + tx * 4 + jj) * 40 + pl] = __float2bfloat16(ov[jj + 4]);
        }
    }
    __syncthreads();
    #pragma unroll
    for (int q = 0; q < 4; q++)
        *(short8*)(ucm + (size_t)tid * M_ + m0 + q * 8) = *(short8*)&lt[tid * 40 + q * 8];
}

// ---------------------------------------------------------------------------
// FUSED SSM: block = (channel, batch). Phase1: chunk-state MFMA -> LDS.
// Phase2: serial scan in LDS. Phase3: Toeplitz conv MFMA + carry + GELU.
__global__ __launch_bounds__(256) void k_ssm(const __hip_bfloat16* __restrict__ ucm,
    const __hip_bfloat16* __restrict__ mt, const __hip_bfloat16* __restrict__ mw,
    const __hip_bfloat16* __restrict__ mv, const float* __restrict__ ws, int layer,
    const float* __restrict__ Dp, __hip_bfloat16* __restrict__ ycm)
{
    __shared__ __hip_bfloat16 st[CHK * 64];   // 16 KB: [128 chunks][64 state-bf16]
    int h = blockIdx.x >> 2, b = blockIdx.x & 3;
    int tid = threadIdx.x, w = tid >> 6, l = tid & 63, l15 = l & 15, l4 = l >> 4;
    const __hip_bfloat16* ub = ucm + (size_t)h * M_ + (size_t)b * L_;
    // ---- phase 1: states S[g][m] = sum_j Wtr[m][j] u[g*64+j]
    {
        const __hip_bfloat16* bbase = mw + (size_t)h * 4096 + l15 * 64 + l4 * 8;
        #pragma unroll
        for (int half = 0; half < 2; half++) {
            int g0 = (w + half * 4) * 16;
            f32x4 acc[4];
            #pragma unroll
            for (int nj = 0; nj < 4; nj++) acc[nj] = (f32x4)0.f;
            #pragma unroll
            for (int ks = 0; ks < 2; ks++) {
                bf16x8 a = *(const bf16x8*)(ub + (size_t)(g0 + l15) * 64 + l4 * 8 + ks * 32);
                #pragma unroll
                for (int nj = 0; nj < 4; nj++) {
                    bf16x8 bb = *(const bf16x8*)(bbase + nj * 16 * 64 + ks * 32);
                    acc[nj] = __builtin_amdgcn_mfma_f32_16x16x32_bf16(a, bb, acc[nj], 0, 0, 0);
                }
            }
            #pragma unroll
            for (int nj = 0; nj < 4; nj++)
                #pragma unroll
                for (int r = 0; r < 4; r++)
                    st[(g0 + l4 * 4 + r) * 64 + nj * 16 + l15] = __float2bfloat16(acc[nj][r]);
        }
    }
    __syncthreads();
    // ---- phase 2: serial scan over 128 chunks (32 threads, one per state-pair)
    if (tid < 32) {
        int n = tid;
        float2 wl = ((const float2*)(ws + OFF_PWLC))[(size_t)layer * H_ * N2_ + h * 32 + n];
        float ar = 0.f, ai = 0.f;
        __hip_bfloat162* base = (__hip_bfloat162*)st + n;
        for (int c = 0; c < CHK; c++) {
            float2 v = __bfloat1622float2(base[c * 32]);
            base[c * 32] = __float22bfloat162_rn(make_float2(ar, ai));
            float tr = fmaf(wl.x, ar, v.x); tr = fmaf(-wl.y, ai, tr);
            float ti = fmaf(wl.x, ai, v.y); ti = fmaf(wl.y, ar, ti);
            ar = tr; ai = ti;
        }
    }
    __syncthreads();
    // ---- phase 3: Y[g][t] = sum_j Ttr[t][j] u[g*64+j] + sum_m Vtr[t][m] Sin[g][m]
    {
        const __hip_bfloat16* bt = mt + (size_t)h * 4096 + l15 * 64 + l4 * 8;
        const __hip_bfloat16* bv = mv + (size_t)h * 4096 + l15 * 64 + l4 * 8;
        float Dh = Dp[layer * H_ + h];
        __hip_bfloat16* yb = ycm + (size_t)h * M_ + (size_t)b * L_;
        #pragma unroll
        for (int half = 0; half < 2; half++) {
            int g0 = (w + half * 4) * 16;
            f32x4 acc[4];
            #pragma unroll
            for (int nj = 0; nj < 4; nj++) acc[nj] = (f32x4)0.f;
            #pragma unroll
            for (int ks = 0; ks < 2; ks++) {
                bf16x8 a = *(const bf16x8*)(ub + (size_t)(g0 + l15) * 64 + l4 * 8 + ks * 32);
                #pragma unroll
                for (int nj = 0; nj < 4; nj++) {
                    bf16x8 bb = *(const bf16x8*)(bt + nj * 16 * 64 + ks * 32);
                    acc[nj] = __builtin_amdgcn_mfma_f32_16x16x32_bf16(a, bb, acc[nj], 0, 0, 0);
                }
            }
            #pragma unroll
            for (int ks = 0; ks < 2; ks++) {
                bf16x8 a = *(const bf16x8*)(st + (g0 + l15) * 64 + l4 * 8 + ks * 32);
                #pragma unroll
                for (int nj = 0; nj < 4; nj++) {
                    bf16x8 bb = *(const bf16x8*)(bv + nj * 16 * 64 + ks * 32);
                    acc[nj] = __builtin_amdgcn_mfma_f32_16x16x32_bf16(a, bb, acc[nj], 0, 0, 0);
                }
            }
            #pragma unroll
            for (int nj = 0; nj < 4; nj++)
                #pragma unroll
                for (int r = 0; r < 4; r++) {
                    int g = g0 + l4 * 4 + r;
                    size_t p = (size_t)g * 64 + nj * 16 + l15;
                    float uv = __bfloat162float(ub[p]);
                    float v = fmaf(Dh, uv, acc[nj][r]);
                    float gg = 0.7978845608028654f * fmaf(0.044715f * v, v * v, v);
                    float yv = v / (1.f + __expf(-2.f * gg));
                    yb[p] = __float2bfloat16(yv);
                }
        }
    }
}

// ---------------------------------------------------------------------------
// y_cm -> y_pm transpose
__global__ __launch_bounds__(256) void k_y2pm(const __hip_bfloat16* __restrict__ ycm,
    __hip_bfloat16* __restrict__ ypm)
{
    __shared__ __hip_bfloat16 lds[64][68];
    int pos0 = blockIdx.x * 64, ch0 = blockIdx.y * 64;
    int tid = threadIdx.x;
    int ch = tid >> 2, p0 = (tid & 3) * 16;
    const __hip_bfloat16* src = ycm + (size_t)(ch0 + ch) * M_ + pos0 + p0;
    #pragma unroll
    for (int k = 0; k < 2; k++)
        *(short8*)&lds[ch][p0 + k*8] = *(const short8*)(src + k*8);
    __syncthreads();
    int pp = tid >> 2, c0 = (tid & 3) * 16;
    alignas(16) __hip_bfloat16 row[16];
    #pragma unroll
    for (int k = 0; k < 16; k++) row[k] = lds[c0 + k][pp];
    size_t base = (size_t)(pos0 + pp) * H_ + ch0 + c0;
    *(short8*)(ypm + base)     = *(short8*)&row[0];
    *(short8*)(ypm + base + 8) = *(short8*)&row[8];
}

// ---------------------------------------------------------------------------
// fused MFMA GLU+LN: BM=32, grid 1024; residual h prefetched into VGPRs early
__global__ __launch_bounds__(256) void k_glu_mfma(
    const __hip_bfloat16* __restrict__ yb,   // [M,256] bf16 pm
    float* __restrict__ h,                   // [M,256] f32 in/out
    const __hip_bfloat16* __restrict__ wob,  // [512,256] bf16
    const float* __restrict__ bo, const float* __restrict__ lnw,
    const float* __restrict__ lnb, __hip_bfloat16* __restrict__ un)
{
    int tid = threadIdx.x;
    int w = tid >> 6, l = tid & 63, l15 = l & 15, l4 = l >> 4;
    int m0 = blockIdx.x * 32;
    int nv = w * 64;
    // prefetch residual h (HBM latency hides under the K-loop MFMAs)
    float hres[2][4][4];
    #pragma unroll
    for (int mi = 0; mi < 2; mi++)
        #pragma unroll
        for (int r = 0; r < 4; r++)
            #pragma unroll
            for (int nj = 0; nj < 4; nj++)
                hres[mi][nj][r] = h[(size_t)(m0 + mi * 16 + l4 * 4 + r) * H_ + nv + nj * 16 + l15];

    f32x4 accv[2][4], accg[2][4];
    #pragma unroll
    for (int mi = 0; mi < 2; mi++)
        #pragma unroll
        for (int nj = 0; nj < 4; nj++) { accv[mi][nj] = (f32x4)0.f; accg[mi][nj] = (f32x4)0.f; }

    #pragma unroll 4
    for (int ks = 0; ks < 8; ks++) {
        int k0 = ks * 32 + l4 * 8;
        bf16x8 a0 = *(const bf16x8*)(yb + (size_t)(m0 + l15) * H_ + k0);
        bf16x8 a1 = *(const bf16x8*)(yb + (size_t)(m0 + 16 + l15) * H_ + k0);
        #pragma unroll
        for (int nj = 0; nj < 4; nj++) {
            bf16x8 bv = *(const bf16x8*)(wob + (size_t)(nv + nj * 16 + l15) * H_ + k0);
            bf16x8 bg = *(const bf16x8*)(wob + (size_t)(256 + nv + nj * 16 + l15) * H_ + k0);
            accv[0][nj] = __builtin_amdgcn_mfma_f32_16x16x32_bf16(a0, bv, accv[0][nj], 0, 0, 0);
            accg[0][nj] = __builtin_amdgcn_mfma_f32_16x16x32_bf16(a0, bg, accg[0][nj], 0, 0, 0);
            accv[1][nj] = __builtin_amdgcn_mfma_f32_16x16x32_bf16(a1, bv, accv[1][nj], 0, 0, 0);
            accg[1][nj] = __builtin_amdgcn_mfma_f32_16x16x32_bf16(a1, bg, accg[1][nj], 0, 0, 0);
        }
    }

    float bov[4], bog[4], lw[4], lb[4];
    #pragma unroll
    for (int nj = 0; nj < 4; nj++) {
        int cn = nv + nj * 16 + l15;
        bov[nj] = bo[cn]; bog[nj] = bo[256 + cn];
        lw[nj] = lnw[cn]; lb[nj] = lnb[cn];
    }
    __shared__ float red[4][32][2];
    __shared__ __hip_bfloat16 lt[256 * 40];
    #pragma unroll
    for (int mi = 0; mi < 2; mi++) {
        #pragma unroll
        for (int r = 0; r < 4; r++) {
            int lr = mi * 16 + l4 * 4 + r;
            float s = 0.f, ss = 0.f;
            #pragma unroll
            for (int nj = 0; nj < 4; nj++) {
                float uv = accv[mi][nj][r] + bov[nj];
                float ug = accg[mi][nj][r] + bog[nj];
                float z = uv / (1.f + __expf(-ug));
                float v = z + hres[mi][nj][r];
                accv[mi][nj][r] = v;
                s += v; ss += v * v;
            }
            #pragma unroll
            for (int off = 1; off < 16; off <<= 1) {
                s  += __shfl_xor(s, off);
                ss += __shfl_xor(ss, off);
            }
            if (l15 == 0) { red[w][lr][0] = s; red[w][lr][1] = ss; }
        }
    }
    __syncthreads();
    #pragma unroll
    for (int mi = 0; mi < 2; mi++) {
        #pragma unroll
        for (int r = 0; r < 4; r++) {
            int lr = mi * 16 + l4 * 4 + r;
            size_t row = (size_t)(m0 + lr);
            float s  = red[0][lr][0] + red[1][lr][0] + red[2][lr][0] + red[3][lr][0];
            float ss = red[0][lr][1] + red[1][lr][1] + red[2][lr][1] + red[3][lr][1];
            float mu = s * (1.f / 256.f);
            float var = ss * (1.f / 256.f) - mu * mu;
            float rstd = rsqrtf(var + 1e-5f);
            #pragma unroll
            for (int nj = 0; nj < 4; nj++) {
                int cn = nv + nj * 16 + l15;
                float val = (accv[mi][nj][r] - mu) * rstd * lw[nj] + lb[nj];
                h[row * H_ + cn] = val;
                lt[cn * 40 + lr] = __float2bfloat16(val);
            }
        }
    }
    __syncthreads();
    #pragma unroll
    for (int q = 0; q < 4; q++)
        *(short8*)(un + (size_t)tid * M_ + m0 + q * 8) = *(short8*)&lt[tid * 40 + q * 8];
}

// ---------------------------------------------------------------------------
__global__ __launch_bounds__(256) void k_decoder(const float* __restrict__ h,
    const float* __restrict__ out_W, const float* __restrict__ out_b,
    float* __restrict__ out)
{
    __shared__ float hs[16][260];
    __shared__ float wl[10][260];
    int p0 = blockIdx.x * 16;
    int tid = threadIdx.x;
    const float4* h4 = (const float4*)h;
    #pragma unroll
    for (int it = 0; it < 4; it++) {
        int q = it * 256 + tid;
        int r = q >> 6, k4 = q & 63;
        float4 v = h4[(size_t)(p0 + r) * 64 + k4];
        *(float4*)&hs[r][k4 * 4] = v;
    }
    for (int q = tid; q < 640; q += 256) {
        int r = q / 64, k4 = q % 64;
        *(float4*)&wl[r][k4 * 4] = ((const float4*)out_W)[q];
    }
    __syncthreads();
    int slot = tid & 15, pl = tid >> 4;
    if (slot < DOUT) {
        float a0 = 0.f, a1 = 0.f, a2 = 0.f, a3 = 0.f;
        #pragma unroll 8
        for (int k = 0; k < 256; k += 4) {
            a0 = fmaf(hs[pl][k + 0], wl[slot][k + 0], a0);
            a1 = fmaf(hs[pl][k + 1], wl[slot][k + 1], a1);
            a2 = fmaf(hs[pl][k + 2], wl[slot][k + 2], a2);
            a3 = fmaf(hs[pl][k + 3], wl[slot][k + 3], a3);
        }
        out[(size_t)(p0 + pl) * DOUT + slot] = (a0 + a1) + (a2 + a3) + out_b[slot];
    }
}

// ---------------------------------------------------------------------------
extern "C" void kernel_launch(void* const* d_in, const int* in_sizes, int n_in,
                              void* d_out, int out_size, void* d_ws, size_t ws_size,
                              hipStream_t stream)
{
    (void)in_sizes; (void)n_in; (void)out_size; (void)ws_size;
    const float* x        = (const float*)d_in[0];
    const float* enc_W    = (const float*)d_in[1];
    const float* enc_b    = (const float*)d_in[2];
    const float* log_dt   = (const float*)d_in[3];
    const float* log_A_re = (const float*)d_in[4];
    const float* A_im     = (const float*)d_in[5];
    const float* C_re     = (const float*)d_in[6];
    const float* C_im     = (const float*)d_in[7];
    const float* Dp       = (const float*)d_in[8];
    const float* Wo       = (const float*)d_in[9];
    const float* bo       = (const float*)d_in[10];
    const float* lnw      = (const float*)d_in[11];
    const float* lnb      = (const float*)d_in[12];
    const float* out_W    = (const float*)d_in[13];
    const float* out_b    = (const float*)d_in[14];
    float* ws = (float*)d_ws;
    float* h  = ws + OFF_H;
    __hip_bfloat16* ucm = (__hip_bfloat16*)(ws + OFF_UCM);
    __hip_bfloat16* ycm = (__hip_bfloat16*)(ws + OFF_YCM);
    __hip_bfloat16* ypm = (__hip_bfloat16*)(ws + OFF_ST);
    __hip_bfloat16* mt = (__hip_bfloat16*)(ws + OFF_MT);
    __hip_bfloat16* mw = (__hip_bfloat16*)(ws + OFF_MW);
    __hip_bfloat16* mv = (__hip_bfloat16*)(ws + OFF_MV);
    __hip_bfloat16* wob = (__hip_bfloat16*)(ws + OFF_WOB);

    k_params<<<NL_ * H_ * N2_ / 256, 256, 0, stream>>>(log_dt, log_A_re, A_im, C_re, C_im, ws);
    dim3 tb(32, 8);
    k_transpose<<<dim3(DIN / 32, H_ / 32), tb, 0, stream>>>(enc_W, ws + OFF_EWT, H_, DIN);
    k_wcvt<<<(NL_ * 2 * H_ * H_ / 4 + 255) / 256, 256, 0, stream>>>(Wo, wob, NL_ * 2 * H_ * H_ / 4);
    k_encoder<<<M_ / 32, 256, 0, stream>>>(x, ws + OFF_EWT, enc_b, h, ucm);
    for (int i = 0; i < NL_; i++) {
        k_mats<<<H_, 256, 0, stream>>>(ws, i, mt, mw, mv);
        k_ssm<<<H_ * B_, 256, 0, stream>>>(ucm, mt, mw, mv, ws, i, Dp, ycm);
        k_y2pm<<<dim3(M_ / 64, H_ / 64), 256, 0, stream>>>(ycm, ypm);
        k_glu_mfma<<<M_ / 32, 256, 0, stream>>>(ypm, h,
            wob + (size_t)i * 2 * H_ * H_, bo + (size_t)i * 2 * H_,
            lnw + (size_t)i * H_, lnb + (size_t)i * H_, ucm);
    }
    k_decoder<<<M_ / 16, 256, 0, stream>>>(h, out_W, out_b, (float*)d_out);
}

// Round 7
// 500.121 us; speedup vs baseline: 1.6263x; 1.0186x over previous
//
#include <hip/hip_runtime.h>
#include <hip/hip_bf16.h>

// ---------------------------------------------------------------------------
// S4D stack, MFMA everywhere:
// encoder GEMM(+cm write) -> 4x[ mats; fused SSM (state MFMA + LDS scan +
//   Toeplitz conv MFMA); cm->pm transpose; GLU MFMA + LN (+cm write) ] -> dec.
// h fp32 position-major; u/y bf16 channel-major; ws ~92 MB.
// ---------------------------------------------------------------------------

constexpr int B_ = 4, L_ = 8192, DIN = 64, H_ = 256, N2_ = 32, NL_ = 4, DOUT = 10;
constexpr int LC = 64, CHK = L_ / LC;     // 128 chunks/batch
constexpr int GCH = B_ * CHK;             // 512 global chunks
constexpr int M_ = B_ * L_;               // 32768 positions

// ws layout in float slots
constexpr size_t OFF_H    = 0;                         // f32 [M][H]
constexpr size_t OFF_WOB  = 8388608;                   // bf16 Wo NL*512*256
constexpr size_t OFF_PW   = 8650752;                   // (legacy)
constexpr size_t OFF_PCT  = 8716288;                   // f32 Ct2 pairs
constexpr size_t OFF_PWLC = 8781824;                   // f32 w^64 pairs
constexpr size_t OFF_PZ   = 8847360;                   // f32 z=dtA pairs
constexpr size_t OFF_EWT  = 8912896;                   // f32 enc W^T
constexpr size_t OFF_UCM  = 8929280;                   // bf16 [H][M] u cm
constexpr size_t OFF_YCM  = 13123584;                  // bf16 [H][M] y cm
constexpr size_t OFF_ST   = 17317888;                  // bf16 y_pm [M][H]
constexpr size_t OFF_MT   = 21512192;                  // bf16 Ttr [H][64][64]
constexpr size_t OFF_MW   = 22036480;                  // bf16 Wtr
constexpr size_t OFF_MV   = 22560768;                  // bf16 Vtr
// end 23085056 slots = 92.3 MB

typedef short bf16x8 __attribute__((ext_vector_type(8)));
typedef short short8 __attribute__((ext_vector_type(8)));
typedef float f32x4  __attribute__((ext_vector_type(4)));

// ---------------------------------------------------------------------------
__global__ __launch_bounds__(256) void k_params(
    const float* __restrict__ log_dt, const float* __restrict__ log_A_re,
    const float* __restrict__ A_im, const float* __restrict__ C_re,
    const float* __restrict__ C_im, float* __restrict__ ws)
{
    int idx = blockIdx.x * 256 + threadIdx.x;     // over NL*H*N2
    if (idx >= NL_ * H_ * N2_) return;
    int i  = idx / (H_ * N2_);
    int hh = (idx / N2_) % H_;
    float dt  = expf(log_dt[i * H_ + hh]);
    float Are = -expf(log_A_re[idx]);
    float Aim = A_im[idx];
    float zre = dt * Are, zim = dt * Aim;
    float er  = expf(zre);
    float wre = er * cosf(zim), wim = er * sinf(zim);
    float d   = Are * Are + Aim * Aim;
    float nre = wre - 1.f, nim = wim;
    float qre = (nre * Are + nim * Aim) / d;
    float qim = (nim * Are - nre * Aim) / d;
    float cr = C_re[idx], ci = C_im[idx];
    float ctre = cr * qre - ci * qim;
    float ctim = cr * qim + ci * qre;
    float er2 = expf(zre * (float)LC);
    float wlre = er2 * cosf(zim * (float)LC);
    float wlim = er2 * sinf(zim * (float)LC);
    ((float2*)(ws + OFF_PW))[idx]   = make_float2(wre, wim);
    ((float2*)(ws + OFF_PCT))[idx]  = make_float2(2.f * ctre, 2.f * ctim);
    ((float2*)(ws + OFF_PWLC))[idx] = make_float2(wlre, wlim);
    ((float2*)(ws + OFF_PZ))[idx]   = make_float2(zre, zim);
}

// ---------------------------------------------------------------------------
// per-channel bf16 matrices: Ttr[t][j]=k[t-j], Wtr[m][j], Vtr[t][m]
__global__ __launch_bounds__(256) void k_mats(const float* __restrict__ ws,
    int layer, __hip_bfloat16* __restrict__ mt, __hip_bfloat16* __restrict__ mw,
    __hip_bfloat16* __restrict__ mv)
{
    int h = blockIdx.x, tid = threadIdx.x;
    __shared__ float zre[32], zim[32], ctr[32], cti[32], kv[64];
    if (tid < 32) {
        float2 z = ((const float2*)(ws + OFF_PZ))[(size_t)layer*H_*N2_ + h*N2_ + tid];
        float2 c = ((const float2*)(ws + OFF_PCT))[(size_t)layer*H_*N2_ + h*N2_ + tid];
        zre[tid] = z.x; zim[tid] = z.y; ctr[tid] = c.x; cti[tid] = c.y;
    }
    __syncthreads();
    if (tid < 64) {
        float d = (float)tid, acc = 0.f;
        for (int n = 0; n < 32; n++) {
            float er = expf(zre[n] * d);
            float co = cosf(zim[n] * d), si = sinf(zim[n] * d);
            acc += er * (ctr[n] * co - cti[n] * si);
        }
        kv[tid] = acc;
    }
    __syncthreads();
    {   // Ttr
        int t = tid >> 2, j0 = (tid & 3) * 16;
        alignas(16) __hip_bfloat16 row[16];
        #pragma unroll
        for (int jj = 0; jj < 16; jj++) {
            int j = j0 + jj;
            row[jj] = __float2bfloat16(j <= t ? kv[t - j] : 0.f);
        }
        *(short8*)(mt + (size_t)h*4096 + t*64 + j0)     = *(short8*)&row[0];
        *(short8*)(mt + (size_t)h*4096 + t*64 + j0 + 8) = *(short8*)&row[8];
    }
    {   // Wtr
        int n = tid >> 3, j0 = (tid & 7) * 8;
        alignas(16) __hip_bfloat16 rre[8], rim[8];
        #pragma unroll
        for (int jj = 0; jj < 8; jj++) {
            float e = (float)(63 - (j0 + jj));
            float er = expf(zre[n] * e);
            rre[jj] = __float2bfloat16(er * cosf(zim[n] * e));
            rim[jj] = __float2bfloat16(er * sinf(zim[n] * e));
        }
        *(short8*)(mw + (size_t)h*4096 + (2*n)*64 + j0)   = *(short8*)&rre[0];
        *(short8*)(mw + (size_t)h*4096 + (2*n+1)*64 + j0) = *(short8*)&rim[0];
    }
    {   // Vtr
        int t = tid >> 2, n0 = (tid & 3) * 8;
        float e = (float)(t + 1);
        alignas(16) __hip_bfloat16 row[16];
        #pragma unroll
        for (int k = 0; k < 8; k++) {
            int n = n0 + k;
            float er = expf(zre[n] * e);
            float wr = er * cosf(zim[n] * e), wi = er * sinf(zim[n] * e);
            row[2*k]   = __float2bfloat16(ctr[n]*wr - cti[n]*wi);
            row[2*k+1] = __float2bfloat16(-(ctr[n]*wi + cti[n]*wr));
        }
        *(short8*)(mv + (size_t)h*4096 + t*64 + 2*n0)     = *(short8*)&row[0];
        *(short8*)(mv + (size_t)h*4096 + t*64 + 2*n0 + 8) = *(short8*)&row[8];
    }
}

// ---------------------------------------------------------------------------
__global__ __launch_bounds__(256) void k_transpose(const float* __restrict__ src,
    float* __restrict__ dst, int R, int Cc)
{
    __shared__ float t[32][33];
    int x = blockIdx.x * 32 + threadIdx.x;
    #pragma unroll
    for (int i = 0; i < 4; i++) {
        int yy = blockIdx.y * 32 + threadIdx.y + i * 8;
        if (x < Cc && yy < R) t[threadIdx.y + i * 8][threadIdx.x] = src[(size_t)yy * Cc + x];
    }
    __syncthreads();
    int xo = blockIdx.y * 32 + threadIdx.x;
    #pragma unroll
    for (int i = 0; i < 4; i++) {
        int yo = blockIdx.x * 32 + threadIdx.y + i * 8;
        if (xo < R && yo < Cc) dst[(size_t)yo * R + xo] = t[threadIdx.x][threadIdx.y + i * 8];
    }
}

// ---------------------------------------------------------------------------
__global__ __launch_bounds__(256) void k_wcvt(const float* __restrict__ src,
    __hip_bfloat16* __restrict__ dst, int n4)
{
    int i = blockIdx.x * 256 + threadIdx.x;
    if (i >= n4) return;
    float4 v = ((const float4*)src)[i];
    union { __hip_bfloat16 b[4]; uint2 u; } o;
    o.b[0] = __float2bfloat16(v.x); o.b[1] = __float2bfloat16(v.y);
    o.b[2] = __float2bfloat16(v.z); o.b[3] = __float2bfloat16(v.w);
    ((uint2*)dst)[i] = o.u;
}

// ---------------------------------------------------------------------------
// encoder: h[M,256] = x @ encWT + b; also writes ucm bf16 channel-major
__global__ __launch_bounds__(256) void k_encoder(const float* __restrict__ x,
    const float* __restrict__ encWT, const float* __restrict__ enc_b,
    float* __restrict__ h, __hip_bfloat16* __restrict__ ucm)
{
    __shared__ float As[DIN][36];
    __shared__ float Bs[32][256];
    int m0 = blockIdx.x * 32;
    int tid = threadIdx.x;
    const float4* x4 = (const float4*)x;
    #pragma unroll
    for (int q = 0; q < 2; q++) {
        int f = tid * 2 + q;
        int row = f >> 4, kq = f & 15;
        float4 v = x4[(size_t)(m0 + row) * 16 + kq];
        As[kq * 4 + 0][row] = v.x; As[kq * 4 + 1][row] = v.y;
        As[kq * 4 + 2][row] = v.z; As[kq * 4 + 3][row] = v.w;
    }
    int tx = tid & 31, ty = tid >> 5;
    float acc[4][8];
    #pragma unroll
    for (int p = 0; p < 4; p++)
        #pragma unroll
        for (int j = 0; j < 8; j++) acc[p][j] = 0.f;
    const float4* w4 = (const float4*)encWT;
    for (int ks = 0; ks < 2; ks++) {
        __syncthreads();
        #pragma unroll
        for (int it = 0; it < 8; it++) {
            int q = it * 256 + tid;
            ((float4*)Bs)[q] = w4[ks * 2048 + q];
        }
        __syncthreads();
        #pragma unroll 8
        for (int kk = 0; kk < 32; kk++) {
            int k = ks * 32 + kk;
            float4 a  = *(const float4*)&As[k][ty * 4];
            float4 b0 = *(const float4*)&Bs[kk][tx * 4];
            float4 b1 = *(const float4*)&Bs[kk][128 + tx * 4];
            float av[4] = {a.x, a.y, a.z, a.w};
            float bv[8] = {b0.x, b0.y, b0.z, b0.w, b1.x, b1.y, b1.z, b1.w};
            #pragma unroll
            for (int p = 0; p < 4; p++)
                #pragma unroll
                for (int j = 0; j < 8; j++)
                    acc[p][j] = fmaf(av[p], bv[j], acc[p][j]);
        }
    }
    float4 eb0 = *(const float4*)&enc_b[tx * 4];
    float4 eb1 = *(const float4*)&enc_b[128 + tx * 4];
    float ebv[8] = {eb0.x, eb0.y, eb0.z, eb0.w, eb1.x, eb1.y, eb1.z, eb1.w};
    __syncthreads();                         // Bs dead -> reuse as lt
    __hip_bfloat16* lt = (__hip_bfloat16*)&Bs[0][0];   // [256][40] bf16
    float4* h4 = (float4*)h;
    #pragma unroll
    for (int p = 0; p < 4; p++) {
        size_t pos = m0 + ty * 4 + p;
        int pl = ty * 4 + p;
        float ov[8];
        #pragma unroll
        for (int j = 0; j < 8; j++) ov[j] = acc[p][j] + ebv[j];
        h4[pos * 64 + tx]      = make_float4(ov[0], ov[1], ov[2], ov[3]);
        h4[pos * 64 + 32 + tx] = make_float4(ov[4], ov[5], ov[6], ov[7]);
        #pragma unroll
        for (int jj = 0; jj < 4; jj++) {
            lt[(tx * 4 + jj) * 40 + pl]       = __float2bfloat16(ov[jj]);
            lt[(128 + tx * 4 + jj) * 40 + pl] = __float2bfloat16(ov[jj + 4]);
        }
    }
    __syncthreads();
    #pragma unroll
    for (int q = 0; q < 4; q++)
        *(short8*)(ucm + (size_t)tid * M_ + m0 + q * 8) = *(short8*)&lt[tid * 40 + q * 8];
}

// ---------------------------------------------------------------------------
// FUSED SSM: block = (channel, batch). Phase1: chunk-state MFMA -> LDS.
// Phase2: serial scan in LDS. Phase3: Toeplitz conv MFMA + carry + GELU.
__global__ __launch_bounds__(256) void k_ssm(const __hip_bfloat16* __restrict__ ucm,
    const __hip_bfloat16* __restrict__ mt, const __hip_bfloat16* __restrict__ mw,
    const __hip_bfloat16* __restrict__ mv, const float* __restrict__ ws, int layer,
    const float* __restrict__ Dp, __hip_bfloat16* __restrict__ ycm)
{
    __shared__ __hip_bfloat16 st[CHK * 64];   // 16 KB: [128 chunks][64 state-bf16]
    int h = blockIdx.x >> 2, b = blockIdx.x & 3;
    int tid = threadIdx.x, w = tid >> 6, l = tid & 63, l15 = l & 15, l4 = l >> 4;
    const __hip_bfloat16* ub = ucm + (size_t)h * M_ + (size_t)b * L_;
    // ---- phase 1: states S[g][m] = sum_j Wtr[m][j] u[g*64+j]
    {
        const __hip_bfloat16* bbase = mw + (size_t)h * 4096 + l15 * 64 + l4 * 8;
        #pragma unroll
        for (int half = 0; half < 2; half++) {
            int g0 = (w + half * 4) * 16;
            f32x4 acc[4];
            #pragma unroll
            for (int nj = 0; nj < 4; nj++) acc[nj] = (f32x4)0.f;
            #pragma unroll
            for (int ks = 0; ks < 2; ks++) {
                bf16x8 a = *(const bf16x8*)(ub + (size_t)(g0 + l15) * 64 + l4 * 8 + ks * 32);
                #pragma unroll
                for (int nj = 0; nj < 4; nj++) {
                    bf16x8 bb = *(const bf16x8*)(bbase + nj * 16 * 64 + ks * 32);
                    acc[nj] = __builtin_amdgcn_mfma_f32_16x16x32_bf16(a, bb, acc[nj], 0, 0, 0);
                }
            }
            #pragma unroll
            for (int nj = 0; nj < 4; nj++)
                #pragma unroll
                for (int r = 0; r < 4; r++)
                    st[(g0 + l4 * 4 + r) * 64 + nj * 16 + l15] = __float2bfloat16(acc[nj][r]);
        }
    }
    __syncthreads();
    // ---- phase 2: serial scan over 128 chunks (32 threads, one per state-pair)
    if (tid < 32) {
        int n = tid;
        float2 wl = ((const float2*)(ws + OFF_PWLC))[(size_t)layer * H_ * N2_ + h * 32 + n];
        float ar = 0.f, ai = 0.f;
        __hip_bfloat162* base = (__hip_bfloat162*)st + n;
        for (int c = 0; c < CHK; c++) {
            float2 v = __bfloat1622float2(base[c * 32]);
            base[c * 32] = __float22bfloat162_rn(make_float2(ar, ai));
            float tr = fmaf(wl.x, ar, v.x); tr = fmaf(-wl.y, ai, tr);
            float ti = fmaf(wl.x, ai, v.y); ti = fmaf(wl.y, ar, ti);
            ar = tr; ai = ti;
        }
    }
    __syncthreads();
    // ---- phase 3: Y[g][t] = sum_j Ttr[t][j] u[g*64+j] + sum_m Vtr[t][m] Sin[g][m]
    {
        const __hip_bfloat16* bt = mt + (size_t)h * 4096 + l15 * 64 + l4 * 8;
        const __hip_bfloat16* bv = mv + (size_t)h * 4096 + l15 * 64 + l4 * 8;
        float Dh = Dp[layer * H_ + h];
        __hip_bfloat16* yb = ycm + (size_t)h * M_ + (size_t)b * L_;
        #pragma unroll
        for (int half = 0; half < 2; half++) {
            int g0 = (w + half * 4) * 16;
            f32x4 acc[4];
            #pragma unroll
            for (int nj = 0; nj < 4; nj++) acc[nj] = (f32x4)0.f;
            #pragma unroll
            for (int ks = 0; ks < 2; ks++) {
                bf16x8 a = *(const bf16x8*)(ub + (size_t)(g0 + l15) * 64 + l4 * 8 + ks * 32);
                #pragma unroll
                for (int nj = 0; nj < 4; nj++) {
                    bf16x8 bb = *(const bf16x8*)(bt + nj * 16 * 64 + ks * 32);
                    acc[nj] = __builtin_amdgcn_mfma_f32_16x16x32_bf16(a, bb, acc[nj], 0, 0, 0);
                }
            }
            #pragma unroll
            for (int ks = 0; ks < 2; ks++) {
                bf16x8 a = *(const bf16x8*)(st + (g0 + l15) * 64 + l4 * 8 + ks * 32);
                #pragma unroll
                for (int nj = 0; nj < 4; nj++) {
                    bf16x8 bb = *(const bf16x8*)(bv + nj * 16 * 64 + ks * 32);
                    acc[nj] = __builtin_amdgcn_mfma_f32_16x16x32_bf16(a, bb, acc[nj], 0, 0, 0);
                }
            }
            #pragma unroll
            for (int nj = 0; nj < 4; nj++)
                #pragma unroll
                for (int r = 0; r < 4; r++) {
                    int g = g0 + l4 * 4 + r;
                    size_t p = (size_t)g * 64 + nj * 16 + l15;
                    float uv = __bfloat162float(ub[p]);
                    float v = fmaf(Dh, uv, acc[nj][r]);
                    float gg = 0.7978845608028654f * fmaf(0.044715f * v, v * v, v);
                    float yv = v / (1.f + __expf(-2.f * gg));
                    yb[p] = __float2bfloat16(yv);
                }
        }
    }
}

// ---------------------------------------------------------------------------
// y_cm -> y_pm transpose
__global__ __launch_bounds__(256) void k_y2pm(const __hip_bfloat16* __restrict__ ycm,
    __hip_bfloat16* __restrict__ ypm)
{
    __shared__ __hip_bfloat16 lds[64][68];
    int pos0 = blockIdx.x * 64, ch0 = blockIdx.y * 64;
    int tid = threadIdx.x;
    int ch = tid >> 2, p0 = (tid & 3) * 16;
    const __hip_bfloat16* src = ycm + (size_t)(ch0 + ch) * M_ + pos0 + p0;
    #pragma unroll
    for (int k = 0; k < 2; k++)
        *(short8*)&lds[ch][p0 + k*8] = *(const short8*)(src + k*8);
    __syncthreads();
    int pp = tid >> 2, c0 = (tid & 3) * 16;
    alignas(16) __hip_bfloat16 row[16];
    #pragma unroll
    for (int k = 0; k < 16; k++) row[k] = lds[c0 + k][pp];
    size_t base = (size_t)(pos0 + pp) * H_ + ch0 + c0;
    *(short8*)(ypm + base)     = *(short8*)&row[0];
    *(short8*)(ypm + base + 8) = *(short8*)&row[8];
}

// ---------------------------------------------------------------------------
// fused MFMA GLU+LN v4: BM=64, 512 threads (8 waves = 2 row-halves x 4 col-
// quarters). A-tile (y) staged in XOR-swizzled LDS once; B from L2; residual
// prefetch; epilogue writes h f32 + next-layer ucm bf16 (LDS transpose).
__global__ __launch_bounds__(512) void k_glu_mfma(
    const __hip_bfloat16* __restrict__ yb,   // [M,256] bf16 pm
    float* __restrict__ h,                   // [M,256] f32 in/out
    const __hip_bfloat16* __restrict__ wob,  // [512,256] bf16
    const float* __restrict__ bo, const float* __restrict__ lnw,
    const float* __restrict__ lnb, __hip_bfloat16* __restrict__ un)
{
    __shared__ __hip_bfloat16 buf[256 * 66];   // A-tile (64x256 swz) / lt reuse
    __shared__ float red[4][64][2];
    int tid = threadIdx.x;
    int w = tid >> 6, l = tid & 63, l15 = l & 15, l4 = l >> 4;
    int m0 = blockIdx.x * 64;
    int mi = w >> 2;                 // row half 0..1
    int nv = (w & 3) * 64;           // col quarter

    // stage A-tile: 64 rows x 256 k, XOR-swizzled: elem = r*256 + (c ^ ((r&7)<<3))
    short8 sreg[4];
    #pragma unroll
    for (int it = 0; it < 4; it++)
        sreg[it] = *(const short8*)(yb + (size_t)m0 * H_ + it * 4096 + tid * 8);
    // residual prefetch (in flight under staging + K-loop)
    float hres[2][4][4];
    #pragma unroll
    for (int sub = 0; sub < 2; sub++)
        #pragma unroll
        for (int r = 0; r < 4; r++)
            #pragma unroll
            for (int nj = 0; nj < 4; nj++)
                hres[sub][nj][r] = h[(size_t)(m0 + mi * 32 + sub * 16 + l4 * 4 + r) * H_
                                     + nv + nj * 16 + l15];
    #pragma unroll
    for (int it = 0; it < 4; it++) {
        int e = it * 4096 + tid * 8;
        int r = e >> 8, c = e & 255;
        *(short8*)&buf[r * 256 + (c ^ ((r & 7) << 3))] = sreg[it];
    }
    __syncthreads();

    f32x4 accv[2][4], accg[2][4];
    #pragma unroll
    for (int sub = 0; sub < 2; sub++)
        #pragma unroll
        for (int nj = 0; nj < 4; nj++) { accv[sub][nj] = (f32x4)0.f; accg[sub][nj] = (f32x4)0.f; }

    int row0 = mi * 32 + l15;        // row0&7 == row1&7
    int swz = (row0 & 7) << 3;
    #pragma unroll 2
    for (int ks = 0; ks < 8; ks++) {
        int k0 = ks * 32 + l4 * 8;
        int kx = k0 ^ swz;
        bf16x8 a0 = *(const bf16x8*)&buf[row0 * 256 + kx];
        bf16x8 a1 = *(const bf16x8*)&buf[(row0 + 16) * 256 + kx];
        #pragma unroll
        for (int nj = 0; nj < 4; nj++) {
            bf16x8 bv = *(const bf16x8*)(wob + (size_t)(nv + nj * 16 + l15) * H_ + k0);
            bf16x8 bg = *(const bf16x8*)(wob + (size_t)(256 + nv + nj * 16 + l15) * H_ + k0);
            accv[0][nj] = __builtin_amdgcn_mfma_f32_16x16x32_bf16(a0, bv, accv[0][nj], 0, 0, 0);
            accg[0][nj] = __builtin_amdgcn_mfma_f32_16x16x32_bf16(a0, bg, accg[0][nj], 0, 0, 0);
            accv[1][nj] = __builtin_amdgcn_mfma_f32_16x16x32_bf16(a1, bv, accv[1][nj], 0, 0, 0);
            accg[1][nj] = __builtin_amdgcn_mfma_f32_16x16x32_bf16(a1, bg, accg[1][nj], 0, 0, 0);
        }
    }

    float bov[4], bog[4], lw[4], lb[4];
    #pragma unroll
    for (int nj = 0; nj < 4; nj++) {
        int cn = nv + nj * 16 + l15;
        bov[nj] = bo[cn]; bog[nj] = bo[256 + cn];
        lw[nj] = lnw[cn]; lb[nj] = lnb[cn];
    }
    #pragma unroll
    for (int sub = 0; sub < 2; sub++) {
        #pragma unroll
        for (int r = 0; r < 4; r++) {
            int lr = mi * 32 + sub * 16 + l4 * 4 + r;
            float s = 0.f, ss = 0.f;
            #pragma unroll
            for (int nj = 0; nj < 4; nj++) {
                float uv = accv[sub][nj][r] + bov[nj];
                float ug = accg[sub][nj][r] + bog[nj];
                float z = uv / (1.f + __expf(-ug));
                float v = z + hres[sub][nj][r];
                accv[sub][nj][r] = v;
                s += v; ss += v * v;
            }
            #pragma unroll
            for (int off = 1; off < 16; off <<= 1) {
                s  += __shfl_xor(s, off);
                ss += __shfl_xor(ss, off);
            }
            if (l15 == 0) { red[w & 3][lr][0] = s; red[w & 3][lr][1] = ss; }
        }
    }
    __syncthreads();                 // also: A region now dead -> reuse as lt[256][66]
    #pragma unroll
    for (int sub = 0; sub < 2; sub++) {
        #pragma unroll
        for (int r = 0; r < 4; r++) {
            int lr = mi * 32 + sub * 16 + l4 * 4 + r;
            size_t row = (size_t)(m0 + lr);
            float s  = red[0][lr][0] + red[1][lr][0] + red[2][lr][0] + red[3][lr][0];
            float ss = red[0][lr][1] + red[1][lr][1] + red[2][lr][1] + red[3][lr][1];
            float mu = s * (1.f / 256.f);
            float var = ss * (1.f / 256.f) - mu * mu;
            float rstd = rsqrtf(var + 1e-5f);
            #pragma unroll
            for (int nj = 0; nj < 4; nj++) {
                int cn = nv + nj * 16 + l15;
                float val = (accv[sub][nj][r] - mu) * rstd * lw[nj] + lb[nj];
                h[row * H_ + cn] = val;
                buf[cn * 66 + lr] = __float2bfloat16(val);
            }
        }
    }
    __syncthreads();
    {   // ucm write: thread -> channel tid>>1, 32 positions
        int ch = tid >> 1, p0 = (tid & 1) * 32;
        #pragma unroll
        for (int q = 0; q < 4; q++)
            *(short8*)(un + (size_t)ch * M_ + m0 + p0 + q * 8)
                = *(short8*)&buf[ch * 66 + p0 + q * 8];
    }
}

// ---------------------------------------------------------------------------
__global__ __launch_bounds__(256) void k_decoder(const float* __restrict__ h,
    const float* __restrict__ out_W, const float* __restrict__ out_b,
    float* __restrict__ out)
{
    __shared__ float hs[16][260];
    __shared__ float wl[10][260];
    int p0 = blockIdx.x * 16;
    int tid = threadIdx.x;
    const float4* h4 = (const float4*)h;
    #pragma unroll
    for (int it = 0; it < 4; it++) {
        int q = it * 256 + tid;
        int r = q >> 6, k4 = q & 63;
        float4 v = h4[(size_t)(p0 + r) * 64 + k4];
        *(float4*)&hs[r][k4 * 4] = v;
    }
    for (int q = tid; q < 640; q += 256) {
        int r = q / 64, k4 = q % 64;
        *(float4*)&wl[r][k4 * 4] = ((const float4*)out_W)[q];
    }
    __syncthreads();
    int slot = tid & 15, pl = tid >> 4;
    if (slot < DOUT) {
        float a0 = 0.f, a1 = 0.f, a2 = 0.f, a3 = 0.f;
        #pragma unroll 8
        for (int k = 0; k < 256; k += 4) {
            a0 = fmaf(hs[pl][k + 0], wl[slot][k + 0], a0);
            a1 = fmaf(hs[pl][k + 1], wl[slot][k + 1], a1);
            a2 = fmaf(hs[pl][k + 2], wl[slot][k + 2], a2);
            a3 = fmaf(hs[pl][k + 3], wl[slot][k + 3], a3);
        }
        out[(size_t)(p0 + pl) * DOUT + slot] = (a0 + a1) + (a2 + a3) + out_b[slot];
    }
}

// ---------------------------------------------------------------------------
extern "C" void kernel_launch(void* const* d_in, const int* in_sizes, int n_in,
                              void* d_out, int out_size, void* d_ws, size_t ws_size,
                              hipStream_t stream)
{
    (void)in_sizes; (void)n_in; (void)out_size; (void)ws_size;
    const float* x        = (const float*)d_in[0];
    const float* enc_W    = (const float*)d_in[1];
    const float* enc_b    = (const float*)d_in[2];
    const float* log_dt   = (const float*)d_in[3];
    const float* log_A_re = (const float*)d_in[4];
    const float* A_im     = (const float*)d_in[5];
    const float* C_re     = (const float*)d_in[6];
    const float* C_im     = (const float*)d_in[7];
    const float* Dp       = (const float*)d_in[8];
    const float* Wo       = (const float*)d_in[9];
    const float* bo       = (const float*)d_in[10];
    const float* lnw      = (const float*)d_in[11];
    const float* lnb      = (const float*)d_in[12];
    const float* out_W    = (const float*)d_in[13];
    const float* out_b    = (const float*)d_in[14];
    float* ws = (float*)d_ws;
    float* h  = ws + OFF_H;
    __hip_bfloat16* ucm = (__hip_bfloat16*)(ws + OFF_UCM);
    __hip_bfloat16* ycm = (__hip_bfloat16*)(ws + OFF_YCM);
    __hip_bfloat16* ypm = (__hip_bfloat16*)(ws + OFF_ST);
    __hip_bfloat16* mt = (__hip_bfloat16*)(ws + OFF_MT);
    __hip_bfloat16* mw = (__hip_bfloat16*)(ws + OFF_MW);
    __hip_bfloat16* mv = (__hip_bfloat16*)(ws + OFF_MV);
    __hip_bfloat16* wob = (__hip_bfloat16*)(ws + OFF_WOB);

    k_params<<<NL_ * H_ * N2_ / 256, 256, 0, stream>>>(log_dt, log_A_re, A_im, C_re, C_im, ws);
    dim3 tb(32, 8);
    k_transpose<<<dim3(DIN / 32, H_ / 32), tb, 0, stream>>>(enc_W, ws + OFF_EWT, H_, DIN);
    k_wcvt<<<(NL_ * 2 * H_ * H_ / 4 + 255) / 256, 256, 0, stream>>>(Wo, wob, NL_ * 2 * H_ * H_ / 4);
    k_encoder<<<M_ / 32, 256, 0, stream>>>(x, ws + OFF_EWT, enc_b, h, ucm);
    for (int i = 0; i < NL_; i++) {
        k_mats<<<H_, 256, 0, stream>>>(ws, i, mt, mw, mv);
        k_ssm<<<H_ * B_, 256, 0, stream>>>(ucm, mt, mw, mv, ws, i, Dp, ycm);
        k_y2pm<<<dim3(M_ / 64, H_ / 64), 256, 0, stream>>>(ycm, ypm);
        k_glu_mfma<<<M_ / 64, 512, 0, stream>>>(ypm, h,
            wob + (size_t)i * 2 * H_ * H_, bo + (size_t)i * 2 * H_,
            lnw + (size_t)i * H_, lnb + (size_t)i * H_, ucm);
    }
    k_decoder<<<M_ / 16, 256, 0, stream>>>(h, out_W, out_b, (float*)d_out);
}

// Round 8
// 499.565 us; speedup vs baseline: 1.6281x; 1.0011x over previous
//
#include <hip/hip_runtime.h>
#include <hip/hip_bf16.h>

// ---------------------------------------------------------------------------
// S4D stack, MFMA everywhere:
// encoder GEMM(+cm,+hfr) -> 4x[ mats; fused SSM (state MFMA + LDS scan +
//   Toeplitz conv MFMA, cm); GLU MFMA + LN (stages A from cm, hfr residual,
//   writes next ucm) ] -> decoder (reads hfr).
// Residual h stored f32 in MFMA-fragment-contiguous layout (hfr):
//   idx = m0*256 + tid32*32 + sub*16 + nj*4 + r   (m0 = pos&~63)
//   tid32 = (mi*4+nq)*64 + l4*16 + l15 ; row=mi*32+sub*16+l4*4+r ; col=nq*64+nj*16+l15
// ---------------------------------------------------------------------------

constexpr int B_ = 4, L_ = 8192, DIN = 64, H_ = 256, N2_ = 32, NL_ = 4, DOUT = 10;
constexpr int LC = 64, CHK = L_ / LC;     // 128 chunks/batch
constexpr int GCH = B_ * CHK;             // 512 global chunks
constexpr int M_ = B_ * L_;               // 32768 positions

// ws layout in float slots
constexpr size_t OFF_H    = 0;                         // f32 hfr [M*256]
constexpr size_t OFF_WOB  = 8388608;                   // bf16 Wo NL*512*256
constexpr size_t OFF_PW   = 8650752;                   // (legacy)
constexpr size_t OFF_PCT  = 8716288;                   // f32 Ct2 pairs
constexpr size_t OFF_PWLC = 8781824;                   // f32 w^64 pairs
constexpr size_t OFF_PZ   = 8847360;                   // f32 z=dtA pairs
constexpr size_t OFF_EWT  = 8912896;                   // f32 enc W^T
constexpr size_t OFF_UCM  = 8929280;                   // bf16 [H][M] u cm
constexpr size_t OFF_YCM  = 13123584;                  // bf16 [H][M] y cm
constexpr size_t OFF_MT   = 21512192;                  // bf16 Ttr [H][64][64]
constexpr size_t OFF_MW   = 22036480;                  // bf16 Wtr
constexpr size_t OFF_MV   = 22560768;                  // bf16 Vtr
// end 23085056 slots = 92.3 MB

typedef short bf16x8 __attribute__((ext_vector_type(8)));
typedef short short8 __attribute__((ext_vector_type(8)));
typedef float f32x4  __attribute__((ext_vector_type(4)));

// ---------------------------------------------------------------------------
__global__ __launch_bounds__(256) void k_params(
    const float* __restrict__ log_dt, const float* __restrict__ log_A_re,
    const float* __restrict__ A_im, const float* __restrict__ C_re,
    const float* __restrict__ C_im, float* __restrict__ ws)
{
    int idx = blockIdx.x * 256 + threadIdx.x;     // over NL*H*N2
    if (idx >= NL_ * H_ * N2_) return;
    int i  = idx / (H_ * N2_);
    int hh = (idx / N2_) % H_;
    float dt  = expf(log_dt[i * H_ + hh]);
    float Are = -expf(log_A_re[idx]);
    float Aim = A_im[idx];
    float zre = dt * Are, zim = dt * Aim;
    float er  = expf(zre);
    float wre = er * cosf(zim), wim = er * sinf(zim);
    float d   = Are * Are + Aim * Aim;
    float nre = wre - 1.f, nim = wim;
    float qre = (nre * Are + nim * Aim) / d;
    float qim = (nim * Are - nre * Aim) / d;
    float cr = C_re[idx], ci = C_im[idx];
    float ctre = cr * qre - ci * qim;
    float ctim = cr * qim + ci * qre;
    float er2 = expf(zre * (float)LC);
    float wlre = er2 * cosf(zim * (float)LC);
    float wlim = er2 * sinf(zim * (float)LC);
    ((float2*)(ws + OFF_PW))[idx]   = make_float2(wre, wim);
    ((float2*)(ws + OFF_PCT))[idx]  = make_float2(2.f * ctre, 2.f * ctim);
    ((float2*)(ws + OFF_PWLC))[idx] = make_float2(wlre, wlim);
    ((float2*)(ws + OFF_PZ))[idx]   = make_float2(zre, zim);
}

// ---------------------------------------------------------------------------
// per-channel bf16 matrices: Ttr[t][j]=k[t-j], Wtr[m][j], Vtr[t][m]
__global__ __launch_bounds__(256) void k_mats(const float* __restrict__ ws,
    int layer, __hip_bfloat16* __restrict__ mt, __hip_bfloat16* __restrict__ mw,
    __hip_bfloat16* __restrict__ mv)
{
    int h = blockIdx.x, tid = threadIdx.x;
    __shared__ float zre[32], zim[32], ctr[32], cti[32], kv[64];
    if (tid < 32) {
        float2 z = ((const float2*)(ws + OFF_PZ))[(size_t)layer*H_*N2_ + h*N2_ + tid];
        float2 c = ((const float2*)(ws + OFF_PCT))[(size_t)layer*H_*N2_ + h*N2_ + tid];
        zre[tid] = z.x; zim[tid] = z.y; ctr[tid] = c.x; cti[tid] = c.y;
    }
    __syncthreads();
    if (tid < 64) {
        float d = (float)tid, acc = 0.f;
        for (int n = 0; n < 32; n++) {
            float er = expf(zre[n] * d);
            float co = cosf(zim[n] * d), si = sinf(zim[n] * d);
            acc += er * (ctr[n] * co - cti[n] * si);
        }
        kv[tid] = acc;
    }
    __syncthreads();
    {   // Ttr
        int t = tid >> 2, j0 = (tid & 3) * 16;
        alignas(16) __hip_bfloat16 row[16];
        #pragma unroll
        for (int jj = 0; jj < 16; jj++) {
            int j = j0 + jj;
            row[jj] = __float2bfloat16(j <= t ? kv[t - j] : 0.f);
        }
        *(short8*)(mt + (size_t)h*4096 + t*64 + j0)     = *(short8*)&row[0];
        *(short8*)(mt + (size_t)h*4096 + t*64 + j0 + 8) = *(short8*)&row[8];
    }
    {   // Wtr
        int n = tid >> 3, j0 = (tid & 7) * 8;
        alignas(16) __hip_bfloat16 rre[8], rim[8];
        #pragma unroll
        for (int jj = 0; jj < 8; jj++) {
            float e = (float)(63 - (j0 + jj));
            float er = expf(zre[n] * e);
            rre[jj] = __float2bfloat16(er * cosf(zim[n] * e));
            rim[jj] = __float2bfloat16(er * sinf(zim[n] * e));
        }
        *(short8*)(mw + (size_t)h*4096 + (2*n)*64 + j0)   = *(short8*)&rre[0];
        *(short8*)(mw + (size_t)h*4096 + (2*n+1)*64 + j0) = *(short8*)&rim[0];
    }
    {   // Vtr
        int t = tid >> 2, n0 = (tid & 3) * 8;
        float e = (float)(t + 1);
        alignas(16) __hip_bfloat16 row[16];
        #pragma unroll
        for (int k = 0; k < 8; k++) {
            int n = n0 + k;
            float er = expf(zre[n] * e);
            float wr = er * cosf(zim[n] * e), wi = er * sinf(zim[n] * e);
            row[2*k]   = __float2bfloat16(ctr[n]*wr - cti[n]*wi);
            row[2*k+1] = __float2bfloat16(-(ctr[n]*wi + cti[n]*wr));
        }
        *(short8*)(mv + (size_t)h*4096 + t*64 + 2*n0)     = *(short8*)&row[0];
        *(short8*)(mv + (size_t)h*4096 + t*64 + 2*n0 + 8) = *(short8*)&row[8];
    }
}

// ---------------------------------------------------------------------------
__global__ __launch_bounds__(256) void k_transpose(const float* __restrict__ src,
    float* __restrict__ dst, int R, int Cc)
{
    __shared__ float t[32][33];
    int x = blockIdx.x * 32 + threadIdx.x;
    #pragma unroll
    for (int i = 0; i < 4; i++) {
        int yy = blockIdx.y * 32 + threadIdx.y + i * 8;
        if (x < Cc && yy < R) t[threadIdx.y + i * 8][threadIdx.x] = src[(size_t)yy * Cc + x];
    }
    __syncthreads();
    int xo = blockIdx.y * 32 + threadIdx.x;
    #pragma unroll
    for (int i = 0; i < 4; i++) {
        int yo = blockIdx.x * 32 + threadIdx.y + i * 8;
        if (xo < R && yo < Cc) dst[(size_t)yo * R + xo] = t[threadIdx.x][threadIdx.y + i * 8];
    }
}

// ---------------------------------------------------------------------------
__global__ __launch_bounds__(256) void k_wcvt(const float* __restrict__ src,
    __hip_bfloat16* __restrict__ dst, int n4)
{
    int i = blockIdx.x * 256 + threadIdx.x;
    if (i >= n4) return;
    float4 v = ((const float4*)src)[i];
    union { __hip_bfloat16 b[4]; uint2 u; } o;
    o.b[0] = __float2bfloat16(v.x); o.b[1] = __float2bfloat16(v.y);
    o.b[2] = __float2bfloat16(v.z); o.b[3] = __float2bfloat16(v.w);
    ((uint2*)dst)[i] = o.u;
}

// ---------------------------------------------------------------------------
// encoder: h = x @ encWT + b; writes hfr (fragment layout f32) + ucm bf16 cm
__global__ __launch_bounds__(256) void k_encoder(const float* __restrict__ x,
    const float* __restrict__ encWT, const float* __restrict__ enc_b,
    float* __restrict__ hfr, __hip_bfloat16* __restrict__ ucm)
{
    __shared__ float As[DIN][36];
    __shared__ float Bs[32][268];          // B-tiles; later f32 stage [32 pos][256 ch]
    int m0e = blockIdx.x * 32;
    int tid = threadIdx.x;
    const float4* x4 = (const float4*)x;
    #pragma unroll
    for (int q = 0; q < 2; q++) {
        int f = tid * 2 + q;
        int row = f >> 4, kq = f & 15;
        float4 v = x4[(size_t)(m0e + row) * 16 + kq];
        As[kq * 4 + 0][row] = v.x; As[kq * 4 + 1][row] = v.y;
        As[kq * 4 + 2][row] = v.z; As[kq * 4 + 3][row] = v.w;
    }
    int tx = tid & 31, ty = tid >> 5;
    float acc[4][8];
    #pragma unroll
    for (int p = 0; p < 4; p++)
        #pragma unroll
        for (int j = 0; j < 8; j++) acc[p][j] = 0.f;
    const float4* w4 = (const float4*)encWT;
    for (int ks = 0; ks < 2; ks++) {
        __syncthreads();
        #pragma unroll
        for (int it = 0; it < 8; it++) {
            int q = it * 256 + tid;
            int row = q >> 6, c4 = q & 63;
            *(float4*)&Bs[row][c4 * 4] = w4[ks * 2048 + q];
        }
        __syncthreads();
        #pragma unroll 8
        for (int kk = 0; kk < 32; kk++) {
            int k = ks * 32 + kk;
            float4 a  = *(const float4*)&As[k][ty * 4];
            float4 b0 = *(const float4*)&Bs[kk][tx * 4];
            float4 b1 = *(const float4*)&Bs[kk][128 + tx * 4];
            float av[4] = {a.x, a.y, a.z, a.w};
            float bv[8] = {b0.x, b0.y, b0.z, b0.w, b1.x, b1.y, b1.z, b1.w};
            #pragma unroll
            for (int p = 0; p < 4; p++)
                #pragma unroll
                for (int j = 0; j < 8; j++)
                    acc[p][j] = fmaf(av[p], bv[j], acc[p][j]);
        }
    }
    float4 eb0 = *(const float4*)&enc_b[tx * 4];
    float4 eb1 = *(const float4*)&enc_b[128 + tx * 4];
    float ebv[8] = {eb0.x, eb0.y, eb0.z, eb0.w, eb1.x, eb1.y, eb1.z, eb1.w};
    __syncthreads();                       // Bs dead -> f32 stage st2[pl][ch]
    #pragma unroll
    for (int p = 0; p < 4; p++) {
        int pl = ty * 4 + p;
        #pragma unroll
        for (int j = 0; j < 4; j++) Bs[pl][tx * 4 + j]       = acc[p][j] + ebv[j];
        #pragma unroll
        for (int j = 0; j < 4; j++) Bs[pl][128 + tx * 4 + j] = acc[p][j + 4] + ebv[j + 4];
    }
    __syncthreads();
    // hfr write: fragment threads, 32 contiguous f32 each
    {
        size_t m0 = (size_t)(m0e & ~63);
        int mi = (m0e >> 5) & 1;
        int nq = tid >> 6, l = tid & 63, l4 = l >> 4, l15 = l & 15;
        int tid32 = (mi * 4 + nq) * 64 + l;
        float* dst = hfr + m0 * 256 + (size_t)tid32 * 32;
        #pragma unroll
        for (int sub = 0; sub < 2; sub++)
            #pragma unroll
            for (int nj = 0; nj < 4; nj++) {
                int pl = sub * 16 + l4 * 4;
                int cn = nq * 64 + nj * 16 + l15;
                float4 o = make_float4(Bs[pl][cn], Bs[pl + 1][cn], Bs[pl + 2][cn], Bs[pl + 3][cn]);
                *(float4*)(dst + sub * 16 + nj * 4) = o;
            }
    }
    // ucm write: thread = channel
    {
        alignas(16) __hip_bfloat16 row[32];
        #pragma unroll
        for (int pl = 0; pl < 32; pl++) row[pl] = __float2bfloat16(Bs[pl][tid]);
        #pragma unroll
        for (int q = 0; q < 4; q++)
            *(short8*)(ucm + (size_t)tid * M_ + m0e + q * 8) = *(short8*)&row[q * 8];
    }
}

// ---------------------------------------------------------------------------
// FUSED SSM: block = (channel, batch). Phase1: chunk-state MFMA -> LDS.
// Phase2: serial scan in LDS. Phase3: Toeplitz conv MFMA + carry + GELU.
__global__ __launch_bounds__(256) void k_ssm(const __hip_bfloat16* __restrict__ ucm,
    const __hip_bfloat16* __restrict__ mt, const __hip_bfloat16* __restrict__ mw,
    const __hip_bfloat16* __restrict__ mv, const float* __restrict__ ws, int layer,
    const float* __restrict__ Dp, __hip_bfloat16* __restrict__ ycm)
{
    __shared__ __hip_bfloat16 st[CHK * 64];   // 16 KB: [128 chunks][64 state-bf16]
    int h = blockIdx.x >> 2, b = blockIdx.x & 3;
    int tid = threadIdx.x, w = tid >> 6, l = tid & 63, l15 = l & 15, l4 = l >> 4;
    const __hip_bfloat16* ub = ucm + (size_t)h * M_ + (size_t)b * L_;
    {
        const __hip_bfloat16* bbase = mw + (size_t)h * 4096 + l15 * 64 + l4 * 8;
        #pragma unroll
        for (int half = 0; half < 2; half++) {
            int g0 = (w + half * 4) * 16;
            f32x4 acc[4];
            #pragma unroll
            for (int nj = 0; nj < 4; nj++) acc[nj] = (f32x4)0.f;
            #pragma unroll
            for (int ks = 0; ks < 2; ks++) {
                bf16x8 a = *(const bf16x8*)(ub + (size_t)(g0 + l15) * 64 + l4 * 8 + ks * 32);
                #pragma unroll
                for (int nj = 0; nj < 4; nj++) {
                    bf16x8 bb = *(const bf16x8*)(bbase + nj * 16 * 64 + ks * 32);
                    acc[nj] = __builtin_amdgcn_mfma_f32_16x16x32_bf16(a, bb, acc[nj], 0, 0, 0);
                }
            }
            #pragma unroll
            for (int nj = 0; nj < 4; nj++)
                #pragma unroll
                for (int r = 0; r < 4; r++)
                    st[(g0 + l4 * 4 + r) * 64 + nj * 16 + l15] = __float2bfloat16(acc[nj][r]);
        }
    }
    __syncthreads();
    if (tid < 32) {
        int n = tid;
        float2 wl = ((const float2*)(ws + OFF_PWLC))[(size_t)layer * H_ * N2_ + h * 32 + n];
        float ar = 0.f, ai = 0.f;
        __hip_bfloat162* base = (__hip_bfloat162*)st + n;
        for (int c = 0; c < CHK; c++) {
            float2 v = __bfloat1622float2(base[c * 32]);
            base[c * 32] = __float22bfloat162_rn(make_float2(ar, ai));
            float tr = fmaf(wl.x, ar, v.x); tr = fmaf(-wl.y, ai, tr);
            float ti = fmaf(wl.x, ai, v.y); ti = fmaf(wl.y, ar, ti);
            ar = tr; ai = ti;
        }
    }
    __syncthreads();
    {
        const __hip_bfloat16* bt = mt + (size_t)h * 4096 + l15 * 64 + l4 * 8;
        const __hip_bfloat16* bv = mv + (size_t)h * 4096 + l15 * 64 + l4 * 8;
        float Dh = Dp[layer * H_ + h];
        __hip_bfloat16* yb = ycm + (size_t)h * M_ + (size_t)b * L_;
        #pragma unroll
        for (int half = 0; half < 2; half++) {
            int g0 = (w + half * 4) * 16;
            f32x4 acc[4];
            #pragma unroll
            for (int nj = 0; nj < 4; nj++) acc[nj] = (f32x4)0.f;
            #pragma unroll
            for (int ks = 0; ks < 2; ks++) {
                bf16x8 a = *(const bf16x8*)(ub + (size_t)(g0 + l15) * 64 + l4 * 8 + ks * 32);
                #pragma unroll
                for (int nj = 0; nj < 4; nj++) {
                    bf16x8 bb = *(const bf16x8*)(bt + nj * 16 * 64 + ks * 32);
                    acc[nj] = __builtin_amdgcn_mfma_f32_16x16x32_bf16(a, bb, acc[nj], 0, 0, 0);
                }
            }
            #pragma unroll
            for (int ks = 0; ks < 2; ks++) {
                bf16x8 a = *(const bf16x8*)(st + (g0 + l15) * 64 + l4 * 8 + ks * 32);
                #pragma unroll
                for (int nj = 0; nj < 4; nj++) {
                    bf16x8 bb = *(const bf16x8*)(bv + nj * 16 * 64 + ks * 32);
                    acc[nj] = __builtin_amdgcn_mfma_f32_16x16x32_bf16(a, bb, acc[nj], 0, 0, 0);
                }
            }
            #pragma unroll
            for (int nj = 0; nj < 4; nj++)
                #pragma unroll
                for (int r = 0; r < 4; r++) {
                    int g = g0 + l4 * 4 + r;
                    size_t p = (size_t)g * 64 + nj * 16 + l15;
                    float uv = __bfloat162float(ub[p]);
                    float v = fmaf(Dh, uv, acc[nj][r]);
                    float gg = 0.7978845608028654f * fmaf(0.044715f * v, v * v, v);
                    float yv = v / (1.f + __expf(-2.f * gg));
                    yb[p] = __float2bfloat16(yv);
                }
        }
    }
}

// ---------------------------------------------------------------------------
// fused MFMA GLU+LN v5: BM=64, 512 threads. A staged from ycm (transpose in
// LDS, XOR-swizzled). hfr residual fragment-contiguous (float4 x8 r/w).
// Epilogue writes hfr + next-layer ucm.
__global__ __launch_bounds__(512) void k_glu_mfma(
    const __hip_bfloat16* __restrict__ ycm,  // [H][M] bf16 cm
    float* __restrict__ hfr,                 // fragment-layout f32
    const __hip_bfloat16* __restrict__ wob,  // [512,256] bf16
    const float* __restrict__ bo, const float* __restrict__ lnw,
    const float* __restrict__ lnb, __hip_bfloat16* __restrict__ un)
{
    __shared__ __hip_bfloat16 buf[256 * 66];   // A-tile (64x256 swz) / lt reuse
    __shared__ float red[4][64][2];
    int tid = threadIdx.x;
    int w = tid >> 6, l = tid & 63, l15 = l & 15, l4 = l >> 4;
    int m0 = blockIdx.x * 64;
    int mi = w >> 2;                 // row half 0..1
    int nv = (w & 3) * 64;           // col quarter

    // ---- A stage from ycm: thread = (ch=tid>>1, 32-pos half)
    int sch = tid >> 1, sp0 = (tid & 1) * 32;
    short8 sv[4];
    {
        const __hip_bfloat16* src = ycm + (size_t)sch * M_ + m0 + sp0;
        #pragma unroll
        for (int it = 0; it < 4; it++) sv[it] = *(const short8*)(src + it * 8);
    }
    // residual prefetch (contiguous 128B per thread; in flight under stage)
    f32x4 hres[2][4];
    {
        const f32x4* hp = (const f32x4*)(hfr + (size_t)m0 * 256 + (size_t)tid * 32);
        #pragma unroll
        for (int sub = 0; sub < 2; sub++)
            #pragma unroll
            for (int nj = 0; nj < 4; nj++) hres[sub][nj] = hp[sub * 4 + nj];
    }
    {   // scatter into swizzled A-tile: buf[row][ch ^ ((row&7)<<3)]
        short* sb = (short*)buf;
        #pragma unroll
        for (int it = 0; it < 4; it++)
            #pragma unroll
            for (int jj = 0; jj < 8; jj++) {
                int row = sp0 + it * 8 + jj;
                sb[row * 256 + (sch ^ ((row & 7) << 3))] = sv[it][jj];
            }
    }
    __syncthreads();

    f32x4 accv[2][4], accg[2][4];
    #pragma unroll
    for (int sub = 0; sub < 2; sub++)
        #pragma unroll
        for (int nj = 0; nj < 4; nj++) { accv[sub][nj] = (f32x4)0.f; accg[sub][nj] = (f32x4)0.f; }

    int row0 = mi * 32 + l15;        // row0&7 == (row0+16)&7... (16 apart flips bit4 only) -> same &7
    int swz = (row0 & 7) << 3;
    #pragma unroll 2
    for (int ks = 0; ks < 8; ks++) {
        int k0 = ks * 32 + l4 * 8;
        int kx = k0 ^ swz;
        bf16x8 a0 = *(const bf16x8*)&buf[row0 * 256 + kx];
        bf16x8 a1 = *(const bf16x8*)&buf[(row0 + 16) * 256 + kx];
        #pragma unroll
        for (int nj = 0; nj < 4; nj++) {
            bf16x8 bv = *(const bf16x8*)(wob + (size_t)(nv + nj * 16 + l15) * H_ + k0);
            bf16x8 bg = *(const bf16x8*)(wob + (size_t)(256 + nv + nj * 16 + l15) * H_ + k0);
            accv[0][nj] = __builtin_amdgcn_mfma_f32_16x16x32_bf16(a0, bv, accv[0][nj], 0, 0, 0);
            accg[0][nj] = __builtin_amdgcn_mfma_f32_16x16x32_bf16(a0, bg, accg[0][nj], 0, 0, 0);
            accv[1][nj] = __builtin_amdgcn_mfma_f32_16x16x32_bf16(a1, bv, accv[1][nj], 0, 0, 0);
            accg[1][nj] = __builtin_amdgcn_mfma_f32_16x16x32_bf16(a1, bg, accg[1][nj], 0, 0, 0);
        }
    }

    float bov[4], bog[4], lw[4], lb[4];
    #pragma unroll
    for (int nj = 0; nj < 4; nj++) {
        int cn = nv + nj * 16 + l15;
        bov[nj] = bo[cn]; bog[nj] = bo[256 + cn];
        lw[nj] = lnw[cn]; lb[nj] = lnb[cn];
    }
    #pragma unroll
    for (int sub = 0; sub < 2; sub++) {
        #pragma unroll
        for (int r = 0; r < 4; r++) {
            int lr = mi * 32 + sub * 16 + l4 * 4 + r;
            float s = 0.f, ss = 0.f;
            #pragma unroll
            for (int nj = 0; nj < 4; nj++) {
                float uv = accv[sub][nj][r] + bov[nj];
                float ug = accg[sub][nj][r] + bog[nj];
                float z = uv / (1.f + __expf(-ug));
                float v = z + hres[sub][nj][r];
                accv[sub][nj][r] = v;
                s += v; ss += v * v;
            }
            #pragma unroll
            for (int off = 1; off < 16; off <<= 1) {
                s  += __shfl_xor(s, off);
                ss += __shfl_xor(ss, off);
            }
            if (l15 == 0) { red[w & 3][lr][0] = s; red[w & 3][lr][1] = ss; }
        }
    }
    __syncthreads();                 // A region dead -> reuse as lt[256][66]
    {
        f32x4* hp = (f32x4*)(hfr + (size_t)m0 * 256 + (size_t)tid * 32);
        #pragma unroll
        for (int sub = 0; sub < 2; sub++) {
            #pragma unroll
            for (int r = 0; r < 4; r++) {
                int lr = mi * 32 + sub * 16 + l4 * 4 + r;
                float s  = red[0][lr][0] + red[1][lr][0] + red[2][lr][0] + red[3][lr][0];
                float ss = red[0][lr][1] + red[1][lr][1] + red[2][lr][1] + red[3][lr][1];
                float mu = s * (1.f / 256.f);
                float var = ss * (1.f / 256.f) - mu * mu;
                float rstd = rsqrtf(var + 1e-5f);
                #pragma unroll
                for (int nj = 0; nj < 4; nj++) {
                    int cn = nv + nj * 16 + l15;
                    float val = (accv[sub][nj][r] - mu) * rstd * lw[nj] + lb[nj];
                    accv[sub][nj][r] = val;
                    buf[cn * 66 + lr] = __float2bfloat16(val);
                }
            }
            #pragma unroll
            for (int nj = 0; nj < 4; nj++) hp[sub * 4 + nj] = accv[sub][nj];
        }
    }
    __syncthreads();
    {   // ucm write: thread -> channel tid>>1, 32 positions
        int ch = tid >> 1, p0 = (tid & 1) * 32;
        #pragma unroll
        for (int q = 0; q < 4; q++)
            *(short8*)(un + (size_t)ch * M_ + m0 + p0 + q * 8)
                = *(short8*)&buf[ch * 66 + p0 + q * 8];
    }
}

// ---------------------------------------------------------------------------
// decoder: reads hfr (fragment layout) via LDS unscramble; 64-pos tiles
__global__ __launch_bounds__(256) void k_decoder(const float* __restrict__ hfr,
    const float* __restrict__ out_W, const float* __restrict__ out_b,
    float* __restrict__ out)
{
    __shared__ float hs[64][260];
    __shared__ float wl[10][260];
    int m0 = blockIdx.x * 64;
    int tid = threadIdx.x;
    #pragma unroll
    for (int half = 0; half < 2; half++) {
        int cid = half * 256 + tid;          // tid32 chunk id
        int cw = cid >> 6, cl = cid & 63;
        int cmi = cw >> 2, cnq = cw & 3, cl4 = cl >> 4, cl15 = cl & 15;
        const f32x4* src = (const f32x4*)(hfr + (size_t)m0 * 256 + (size_t)cid * 32);
        #pragma unroll
        for (int sub = 0; sub < 2; sub++)
            #pragma unroll
            for (int nj = 0; nj < 4; nj++) {
                f32x4 v = src[sub * 4 + nj];
                int row = cmi * 32 + sub * 16 + cl4 * 4;
                int col = cnq * 64 + nj * 16 + cl15;
                hs[row][col] = v[0]; hs[row + 1][col] = v[1];
                hs[row + 2][col] = v[2]; hs[row + 3][col] = v[3];
            }
    }
    for (int q = tid; q < 640; q += 256) {
        int r = q / 64, k4 = q % 64;
        *(float4*)&wl[r][k4 * 4] = ((const float4*)out_W)[q];
    }
    __syncthreads();
    int slot = tid & 15;
    if (slot < DOUT) {
        #pragma unroll
        for (int pass = 0; pass < 4; pass++) {
            int pl = pass * 16 + (tid >> 4);
            float a0 = 0.f, a1 = 0.f, a2 = 0.f, a3 = 0.f;
            #pragma unroll 8
            for (int k = 0; k < 256; k += 4) {
                a0 = fmaf(hs[pl][k + 0], wl[slot][k + 0], a0);
                a1 = fmaf(hs[pl][k + 1], wl[slot][k + 1], a1);
                a2 = fmaf(hs[pl][k + 2], wl[slot][k + 2], a2);
                a3 = fmaf(hs[pl][k + 3], wl[slot][k + 3], a3);
            }
            out[(size_t)(m0 + pl) * DOUT + slot] = (a0 + a1) + (a2 + a3) + out_b[slot];
        }
    }
}

// ---------------------------------------------------------------------------
extern "C" void kernel_launch(void* const* d_in, const int* in_sizes, int n_in,
                              void* d_out, int out_size, void* d_ws, size_t ws_size,
                              hipStream_t stream)
{
    (void)in_sizes; (void)n_in; (void)out_size; (void)ws_size;
    const float* x        = (const float*)d_in[0];
    const float* enc_W    = (const float*)d_in[1];
    const float* enc_b    = (const float*)d_in[2];
    const float* log_dt   = (const float*)d_in[3];
    const float* log_A_re = (const float*)d_in[4];
    const float* A_im     = (const float*)d_in[5];
    const float* C_re     = (const float*)d_in[6];
    const float* C_im     = (const float*)d_in[7];
    const float* Dp       = (const float*)d_in[8];
    const float* Wo       = (const float*)d_in[9];
    const float* bo       = (const float*)d_in[10];
    const float* lnw      = (const float*)d_in[11];
    const float* lnb      = (const float*)d_in[12];
    const float* out_W    = (const float*)d_in[13];
    const float* out_b    = (const float*)d_in[14];
    float* ws = (float*)d_ws;
    float* hfr = ws + OFF_H;
    __hip_bfloat16* ucm = (__hip_bfloat16*)(ws + OFF_UCM);
    __hip_bfloat16* ycm = (__hip_bfloat16*)(ws + OFF_YCM);
    __hip_bfloat16* mt = (__hip_bfloat16*)(ws + OFF_MT);
    __hip_bfloat16* mw = (__hip_bfloat16*)(ws + OFF_MW);
    __hip_bfloat16* mv = (__hip_bfloat16*)(ws + OFF_MV);
    __hip_bfloat16* wob = (__hip_bfloat16*)(ws + OFF_WOB);

    k_params<<<NL_ * H_ * N2_ / 256, 256, 0, stream>>>(log_dt, log_A_re, A_im, C_re, C_im, ws);
    dim3 tb(32, 8);
    k_transpose<<<dim3(DIN / 32, H_ / 32), tb, 0, stream>>>(enc_W, ws + OFF_EWT, H_, DIN);
    k_wcvt<<<(NL_ * 2 * H_ * H_ / 4 + 255) / 256, 256, 0, stream>>>(Wo, wob, NL_ * 2 * H_ * H_ / 4);
    k_encoder<<<M_ / 32, 256, 0, stream>>>(x, ws + OFF_EWT, enc_b, hfr, ucm);
    for (int i = 0; i < NL_; i++) {
        k_mats<<<H_, 256, 0, stream>>>(ws, i, mt, mw, mv);
        k_ssm<<<H_ * B_, 256, 0, stream>>>(ucm, mt, mw, mv, ws, i, Dp, ycm);
        k_glu_mfma<<<M_ / 64, 512, 0, stream>>>(ycm, hfr,
            wob + (size_t)i * 2 * H_ * H_, bo + (size_t)i * 2 * H_,
            lnw + (size_t)i * H_, lnb + (size_t)i * H_, ucm);
    }
    k_decoder<<<M_ / 64, 256, 0, stream>>>(hfr, out_W, out_b, (float*)d_out);
}